// Round 7
// baseline (698.149 us; speedup 1.0000x reference)
//
#include <hip/hip_runtime.h>
#include <hip/hip_bf16.h>
#include <cstdint>
#include <cstddef>

#define NN 100000
#define DD 128
#define NE 1600000
#define NPB 196                 // nodes per bucket
#define NBUCK 511               // ceil(NN / NPB)
#define BCAP 6144               // LDS staging capacity per bucket (lambda=3136)
#define SCHUNK 8192             // edges per block-chunk in bscatter

typedef short bf16x8 __attribute__((ext_vector_type(8)));
typedef float f32x4 __attribute__((ext_vector_type(4)));
typedef unsigned short u16;
typedef unsigned int u32;

__device__ inline float b2f(u16 u) {
    union { u32 i; float f; } c; c.i = ((u32)u) << 16; return c.f;
}
__device__ inline u16 f2b(float f) {
    __hip_bfloat16 h = __float2bfloat16(f);   // RNE
    return *reinterpret_cast<u16*>(&h);
}

// ---------------------------------------------------------------------------
// CSR build, bucketed counting sort (unchanged from round 6).
// ---------------------------------------------------------------------------
__global__ __launch_bounds__(256)
void bcount_kernel(const int* __restrict__ ei, int* __restrict__ bcnt,
                   int n_edges) {
    __shared__ int h[NBUCK];
    for (int i = threadIdx.x; i < NBUCK; i += 256) h[i] = 0;
    __syncthreads();
    int t0 = blockIdx.x * blockDim.x + threadIdx.x;
    int stride = gridDim.x * blockDim.x;
    for (int e = t0; e < n_edges; e += stride)
        atomicAdd(&h[ei[n_edges + e] / NPB], 1);
    __syncthreads();
    for (int i = threadIdx.x; i < NBUCK; i += 256)
        if (h[i]) atomicAdd(&bcnt[i], h[i]);
}

__global__ __launch_bounds__(512)
void bscan_kernel(const int* __restrict__ bcnt, int* __restrict__ base,
                  int* __restrict__ cursor) {
    __shared__ int tmp[512];
    int t = threadIdx.x;
    int v = (t < NBUCK) ? bcnt[t] : 0;
    tmp[t] = v;
    __syncthreads();
    for (int o = 1; o < 512; o <<= 1) {
        int u = (t >= o) ? tmp[t - o] : 0;
        __syncthreads();
        tmp[t] += u;
        __syncthreads();
    }
    int excl = tmp[t] - v;
    if (t < NBUCK) { base[t] = excl; cursor[t] = excl; }
    if (t == NBUCK - 1) base[NBUCK] = excl + v;
}

__global__ __launch_bounds__(256)
void bscatter_kernel(const int* __restrict__ ei, int* __restrict__ cursor,
                     u32* __restrict__ packed, int n_edges) {
    __shared__ int hist[NBUCK];
    const int tid = threadIdx.x;
    const int nchunks = (n_edges + SCHUNK - 1) / SCHUNK;
    for (int ch = blockIdx.x; ch < nchunks; ch += gridDim.x) {
        const int e0 = ch * SCHUNK;
        const int e1 = min(e0 + SCHUNK, n_edges);
        for (int i = tid; i < NBUCK; i += 256) hist[i] = 0;
        __syncthreads();
        for (int e = e0 + tid; e < e1; e += 256)
            atomicAdd(&hist[ei[n_edges + e] / NPB], 1);
        __syncthreads();
        for (int i = tid; i < NBUCK; i += 256) {
            int c = hist[i];
            hist[i] = (c > 0) ? atomicAdd(&cursor[i], c) : 0;
        }
        __syncthreads();
        for (int e = e0 + tid; e < e1; e += 256) {
            int s = ei[e];
            int d = ei[n_edges + e];
            int b = d / NPB;
            int ld = d - b * NPB;
            int pos = atomicAdd(&hist[b], 1);
            packed[pos] = ((u32)ld << 17) | (u32)s;
        }
        __syncthreads();
    }
}

__global__ __launch_bounds__(256)
void blocal_kernel(const u32* __restrict__ packed, const int* __restrict__ base,
                   int* __restrict__ row_ptr, int* __restrict__ ssrc) {
    __shared__ int out_s[BCAP];
    __shared__ int cur_s[NPB];
    __shared__ int excl_s[NPB];
    __shared__ int ws[4];
    __shared__ int wexc[4];

    const int b = blockIdx.x;
    const int tid = threadIdx.x;
    const int lane = tid & 63, wv = tid >> 6;
    const int beg = base[b], end = base[b + 1];
    const int cnt = end - beg;

    if (tid < NPB) cur_s[tid] = 0;
    __syncthreads();
    for (int i = tid; i < cnt; i += 256)
        atomicAdd(&cur_s[packed[beg + i] >> 17], 1);
    __syncthreads();

    int v = (tid < NPB) ? cur_s[tid] : 0;
    int inc = v;
    #pragma unroll
    for (int o = 1; o < 64; o <<= 1) {
        int u = __shfl_up(inc, o);
        if (lane >= o) inc += u;
    }
    if (lane == 63) ws[wv] = inc;
    __syncthreads();
    if (tid == 0) {
        int s = 0;
        #pragma unroll
        for (int k = 0; k < 4; ++k) { wexc[k] = s; s += ws[k]; }
    }
    __syncthreads();
    int excl = inc - v + wexc[wv];
    if (tid < NPB) { excl_s[tid] = excl; }
    int gnode = b * NPB + tid;
    if (tid < NPB && gnode < NN) row_ptr[gnode] = beg + excl;
    if (b == 0 && tid == 0) row_ptr[NN] = NE;
    __syncthreads();
    if (tid < NPB) cur_s[tid] = excl_s[tid];
    __syncthreads();

    if (cnt <= BCAP) {
        for (int i = tid; i < cnt; i += 256) {
            u32 p = packed[beg + i];
            int pos = atomicAdd(&cur_s[p >> 17], 1);
            out_s[pos] = (int)(p & 0x1FFFF);
        }
        __syncthreads();
        for (int i = tid; i < cnt; i += 256) ssrc[beg + i] = out_s[i];
    } else {
        for (int i = tid; i < cnt; i += 256) {
            u32 p = packed[beg + i];
            int pos = atomicAdd(&cur_s[p >> 17], 1);
            ssrc[beg + pos] = (int)(p & 0x1FFFF);
        }
    }
}

// ---------------------------------------------------------------------------
// Conversions
// ---------------------------------------------------------------------------
__global__ __launch_bounds__(256)
void cvt_x_kernel(const float* __restrict__ x, u16* __restrict__ xb, long long n4) {
    long long t = (long long)blockIdx.x * blockDim.x + threadIdx.x;
    long long stride = (long long)gridDim.x * blockDim.x;
    for (; t < n4; t += stride) {
        float4 v = reinterpret_cast<const float4*>(x)[t];
        ushort4 o;
        o.x = f2b(v.x); o.y = f2b(v.y); o.z = f2b(v.z); o.w = f2b(v.w);
        reinterpret_cast<ushort4*>(xb)[t] = o;
    }
}

__global__ __launch_bounds__(256)
void cvt_w_kernel(const float* __restrict__ Wl, const float* __restrict__ Wr,
                  const float* __restrict__ Wp1f, u16* __restrict__ Wcat,
                  u16* __restrict__ Wp1) {
    int t = blockIdx.x * blockDim.x + threadIdx.x;
    const int NCAT = 3 * 128 * 256;
    if (t < NCAT) {
        int layer = t >> 15;
        int rem = t & 32767;
        int d = rem >> 8;
        int k = rem & 255;
        float v = (k < 128) ? Wl[layer * 16384 + d * 128 + k]
                            : Wr[layer * 16384 + d * 128 + (k - 128)];
        Wcat[t] = f2b(v);
    } else if (t < NCAT + 128 * 128) {
        int i = t - NCAT;
        Wp1[i] = f2b(Wp1f[i]);
    }
}

// ---------------------------------------------------------------------------
// Fused layer: gather (CSR) -> [h|prop] @ Wcat^T + b -> L2-normalize -> ReLU.
// Block = 256 thr = 4 waves, strip of 32 nodes.
//  - h half of A-tile staged from global (16B chunks, XOR swizzle).
//  - prop half produced IN LDS by per-wave CSR gather (8 nodes/wave, fp32
//    accum in regs, unroll-4 for MLP), no P buffer round-trip.
//  - then MFMA as before: wave w owns cols [32w,32w+32), B-frags in regs.
// ---------------------------------------------------------------------------
__global__ __launch_bounds__(256)
void layer_kernel(const u16* __restrict__ hin, const int* __restrict__ rp,
                  const int* __restrict__ ssrc, const u16* __restrict__ Wc,
                  const float* __restrict__ b1, const float* __restrict__ b2,
                  u16* __restrict__ out, int n_strips) {
    constexpr int KSTEPS = 8;
    constexpr int ROWB = 512;       // bytes per A row (h 256B + prop 256B)
    __shared__ char a_s[32 * ROWB];
    __shared__ float red_s[32][4];

    const int tid = threadIdx.x;
    const int w = tid >> 6;
    const int l = tid & 63;
    const int q = l >> 4;
    const int c16 = l & 15;

    bf16x8 bfrag[2][KSTEPS];
    int col[2];
    float bias[2];
    #pragma unroll
    for (int t = 0; t < 2; ++t) {
        col[t] = w * 32 + t * 16 + c16;
        bias[t] = b1[col[t]] + b2[col[t]];
        #pragma unroll
        for (int kk = 0; kk < KSTEPS; ++kk)
            bfrag[t][kk] = *reinterpret_cast<const bf16x8*>(
                Wc + (size_t)col[t] * 256 + kk * 32 + q * 8);
    }

    for (int strip = blockIdx.x; strip < n_strips; strip += gridDim.x) {
        const int base = strip * 32;

        // h half: 32 rows x 16 chunks of 16B
        for (int ci = tid; ci < 512; ci += 256) {
            int r = ci >> 4, c = ci & 15;
            *reinterpret_cast<uint4*>(a_s + r * ROWB + ((c ^ (r & 7)) * 16)) =
                *reinterpret_cast<const uint4*>(hin + (size_t)(base + r) * DD + c * 8);
        }

        // prop half: wave w gathers rows w*8 .. w*8+7
        const u16* hb = hin + l * 2;
        for (int j = 0; j < 8; ++j) {
            int r = w * 8 + j;
            int n = base + r;
            int beg = rp[n], end = rp[n + 1];
            float ax = 0.0f, ay = 0.0f;
            int e = beg;
            for (; e + 3 < end; e += 4) {
                int s0 = ssrc[e], s1 = ssrc[e + 1], s2 = ssrc[e + 2], s3 = ssrc[e + 3];
                u32 v0 = *reinterpret_cast<const u32*>(hb + (size_t)s0 * DD);
                u32 v1 = *reinterpret_cast<const u32*>(hb + (size_t)s1 * DD);
                u32 v2 = *reinterpret_cast<const u32*>(hb + (size_t)s2 * DD);
                u32 v3 = *reinterpret_cast<const u32*>(hb + (size_t)s3 * DD);
                union { u32 i; float f; } c;
                c.i = v0 << 16; ax += c.f;
                c.i = v0 & 0xffff0000u; ay += c.f;
                c.i = v1 << 16; ax += c.f;
                c.i = v1 & 0xffff0000u; ay += c.f;
                c.i = v2 << 16; ax += c.f;
                c.i = v2 & 0xffff0000u; ay += c.f;
                c.i = v3 << 16; ax += c.f;
                c.i = v3 & 0xffff0000u; ay += c.f;
            }
            for (; e < end; ++e) {
                u32 v0 = *reinterpret_cast<const u32*>(hb + (size_t)ssrc[e] * DD);
                union { u32 i; float f; } c;
                c.i = v0 << 16; ax += c.f;
                c.i = v0 & 0xffff0000u; ay += c.f;
            }
            u32 o = (u32)f2b(ax) | ((u32)f2b(ay) << 16);
            int c = 16 + (l >> 2);
            *reinterpret_cast<u32*>(
                a_s + r * ROWB + ((c ^ (r & 7)) * 16) + (l & 3) * 4) = o;
        }
        __syncthreads();

        f32x4 acc[2][2] = {};
        #pragma unroll
        for (int kk = 0; kk < KSTEPS; ++kk) {
            int cc = kk * 4 + q;
            bf16x8 a0 = *reinterpret_cast<const bf16x8*>(
                a_s + c16 * ROWB + ((cc ^ (c16 & 7)) * 16));
            bf16x8 a1 = *reinterpret_cast<const bf16x8*>(
                a_s + (16 + c16) * ROWB + ((cc ^ ((16 + c16) & 7)) * 16));
            acc[0][0] = __builtin_amdgcn_mfma_f32_16x16x32_bf16(a0, bfrag[0][kk], acc[0][0], 0, 0, 0);
            acc[0][1] = __builtin_amdgcn_mfma_f32_16x16x32_bf16(a0, bfrag[1][kk], acc[0][1], 0, 0, 0);
            acc[1][0] = __builtin_amdgcn_mfma_f32_16x16x32_bf16(a1, bfrag[0][kk], acc[1][0], 0, 0, 0);
            acc[1][1] = __builtin_amdgcn_mfma_f32_16x16x32_bf16(a1, bfrag[1][kk], acc[1][1], 0, 0, 0);
        }

        float vals[2][2][4];
        float ss[2][4];
        #pragma unroll
        for (int m = 0; m < 2; ++m) {
            #pragma unroll
            for (int reg = 0; reg < 4; ++reg) {
                float s = 0.0f;
                #pragma unroll
                for (int t = 0; t < 2; ++t) {
                    float v = acc[m][t][reg] + bias[t];
                    vals[m][t][reg] = v;
                    s += v * v;
                }
                s += __shfl_xor(s, 1);
                s += __shfl_xor(s, 2);
                s += __shfl_xor(s, 4);
                s += __shfl_xor(s, 8);
                ss[m][reg] = s;
            }
        }
        if (c16 == 0) {
            #pragma unroll
            for (int m = 0; m < 2; ++m)
                #pragma unroll
                for (int reg = 0; reg < 4; ++reg)
                    red_s[m * 16 + q * 4 + reg][w] = ss[m][reg];
        }
        __syncthreads();
        #pragma unroll
        for (int m = 0; m < 2; ++m) {
            #pragma unroll
            for (int reg = 0; reg < 4; ++reg) {
                int row = m * 16 + q * 4 + reg;
                float4 rr = *reinterpret_cast<float4*>(&red_s[row][0]);
                float tot = rr.x + rr.y + rr.z + rr.w;
                float rn = 1.0f / fmaxf(sqrtf(tot), 1e-12f);
                #pragma unroll
                for (int t = 0; t < 2; ++t) {
                    float v = fmaxf(vals[m][t][reg] * rn, 0.0f);
                    out[(size_t)(base + row) * DD + col[t]] = f2b(v);
                }
            }
        }
        __syncthreads();
    }
}

// ---------------------------------------------------------------------------
// post1 GEMM (no gather, no norm): out = h @ Wp1^T + b1
// ---------------------------------------------------------------------------
__global__ __launch_bounds__(256)
void post1_kernel(const u16* __restrict__ hin, const u16* __restrict__ Wc,
                  const float* __restrict__ b1, u16* __restrict__ out,
                  int n_strips) {
    constexpr int KSTEPS = 4;
    constexpr int ROWB = 256;
    __shared__ char a_s[32 * ROWB];

    const int tid = threadIdx.x;
    const int w = tid >> 6;
    const int l = tid & 63;
    const int q = l >> 4;
    const int c16 = l & 15;

    bf16x8 bfrag[2][KSTEPS];
    int col[2];
    float bias[2];
    #pragma unroll
    for (int t = 0; t < 2; ++t) {
        col[t] = w * 32 + t * 16 + c16;
        bias[t] = b1[col[t]];
        #pragma unroll
        for (int kk = 0; kk < KSTEPS; ++kk)
            bfrag[t][kk] = *reinterpret_cast<const bf16x8*>(
                Wc + (size_t)col[t] * 128 + kk * 32 + q * 8);
    }

    for (int strip = blockIdx.x; strip < n_strips; strip += gridDim.x) {
        const int base = strip * 32;
        for (int ci = tid; ci < 512; ci += 256) {
            int r = ci >> 4, c = ci & 15;
            *reinterpret_cast<uint4*>(a_s + r * ROWB + ((c ^ (r & 7)) * 16)) =
                *reinterpret_cast<const uint4*>(hin + (size_t)(base + r) * DD + c * 8);
        }
        __syncthreads();

        f32x4 acc[2][2] = {};
        #pragma unroll
        for (int kk = 0; kk < KSTEPS; ++kk) {
            int cc = kk * 4 + q;
            bf16x8 a0 = *reinterpret_cast<const bf16x8*>(
                a_s + c16 * ROWB + ((cc ^ (c16 & 7)) * 16));
            bf16x8 a1 = *reinterpret_cast<const bf16x8*>(
                a_s + (16 + c16) * ROWB + ((cc ^ ((16 + c16) & 7)) * 16));
            acc[0][0] = __builtin_amdgcn_mfma_f32_16x16x32_bf16(a0, bfrag[0][kk], acc[0][0], 0, 0, 0);
            acc[0][1] = __builtin_amdgcn_mfma_f32_16x16x32_bf16(a0, bfrag[1][kk], acc[0][1], 0, 0, 0);
            acc[1][0] = __builtin_amdgcn_mfma_f32_16x16x32_bf16(a1, bfrag[0][kk], acc[1][0], 0, 0, 0);
            acc[1][1] = __builtin_amdgcn_mfma_f32_16x16x32_bf16(a1, bfrag[1][kk], acc[1][1], 0, 0, 0);
        }

        #pragma unroll
        for (int m = 0; m < 2; ++m)
            #pragma unroll
            for (int reg = 0; reg < 4; ++reg) {
                int row = m * 16 + q * 4 + reg;
                #pragma unroll
                for (int t = 0; t < 2; ++t) {
                    float v = acc[m][t][reg] + bias[t];
                    out[(size_t)(base + row) * DD + col[t]] = f2b(v);
                }
            }
        __syncthreads();
    }
}

// ---------------------------------------------------------------------------
// Post2 + log_softmax (bf16 in, fp32 out)
// ---------------------------------------------------------------------------
__global__ __launch_bounds__(256)
void post2_kernel(const u16* __restrict__ hin, const float* __restrict__ W2,
                  const float* __restrict__ b2, float* __restrict__ out,
                  int n_nodes) {
    __shared__ float w_s[40 * 132];
    __shared__ float row_s[4][DD];
    const int tid = threadIdx.x;

    {
        const float4* gw = reinterpret_cast<const float4*>(W2);
        float4* sw = reinterpret_cast<float4*>(w_s);
        for (int j = tid; j < 40 * 32; j += 256) {
            int r = j >> 5, c = j & 31;
            sw[r * 33 + c] = gw[j];
        }
    }
    __syncthreads();

    const int wave = tid >> 6;
    const int lane = tid & 63;
    const float4* w4 = reinterpret_cast<const float4*>(w_s);
    const int lr = (lane < 40) ? lane : 0;
    const float bias = (lane < 40) ? b2[lr] : 0.0f;

    for (int base = blockIdx.x * 4; base < n_nodes; base += gridDim.x * 4) {
        int n = base + wave;
        bool alive = (n < n_nodes);
        if (alive) {
            row_s[wave][lane] = b2f(hin[(size_t)n * DD + lane]);
            row_s[wave][64 + lane] = b2f(hin[(size_t)n * DD + 64 + lane]);
        }
        __syncthreads();

        float acc = bias;
        const float4* r4 = reinterpret_cast<const float4*>(row_s[wave]);
        #pragma unroll
        for (int c = 0; c < 32; ++c) {
            float4 rv = r4[c];
            float4 wv = w4[lr * 33 + c];
            acc += rv.x * wv.x + rv.y * wv.y + rv.z * wv.z + rv.w * wv.w;
        }

        float m = (alive && lane < 40) ? acc : -INFINITY;
        #pragma unroll
        for (int o = 32; o > 0; o >>= 1) m = fmaxf(m, __shfl_xor(m, o));
        float e = (alive && lane < 40) ? expf(acc - m) : 0.0f;
        #pragma unroll
        for (int o = 32; o > 0; o >>= 1) e += __shfl_xor(e, o);

        if (alive && lane < 40) out[(size_t)n * 40 + lane] = acc - m - logf(e);
        __syncthreads();
    }
}

// ---------------------------------------------------------------------------
extern "C" void kernel_launch(void* const* d_in, const int* in_sizes, int n_in,
                              void* d_out, int out_size, void* d_ws, size_t ws_size,
                              hipStream_t stream) {
    const float* x   = (const float*)d_in[0];
    const int*   ei  = (const int*)d_in[1];
    const float* Wl  = (const float*)d_in[2];
    const float* bl  = (const float*)d_in[3];
    const float* Wr  = (const float*)d_in[4];
    const float* br  = (const float*)d_in[5];
    const float* W1f = (const float*)d_in[6];
    const float* b1  = (const float*)d_in[7];
    const float* W2  = (const float*)d_in[8];
    const float* b2  = (const float*)d_in[9];
    float* outp = (float*)d_out;

    // Workspace: xb | P(unused) | bufA | bufB | Wcat | Wp1 | bcnt | base |
    //            cursor | row_ptr | ssrc | packed
    u16* xb   = (u16*)d_ws;
    u16* P    = xb + (size_t)NN * DD;
    u16* bufA = P + (size_t)NN * DD;
    u16* bufB = bufA + (size_t)NN * DD;
    u16* Wcat = bufB + (size_t)NN * DD;
    u16* Wp1  = Wcat + 3 * 128 * 256;
    int* bcnt    = (int*)(Wp1 + 128 * 128);
    int* base    = bcnt + NBUCK + 1;
    int* cursor  = base + NBUCK + 1;
    int* row_ptr = cursor + NBUCK + 1;
    int* ssrc    = row_ptr + NN + 1;
    u32* packed  = (u32*)(ssrc + NE);

    // CSR build (bucketed counting sort, chunk-reserved scatter)
    hipMemsetAsync(bcnt, 0, (NBUCK + 1) * sizeof(int), stream);
    bcount_kernel<<<128, 256, 0, stream>>>(ei, bcnt, NE);
    bscan_kernel<<<1, 512, 0, stream>>>(bcnt, base, cursor);
    bscatter_kernel<<<(NE + SCHUNK - 1) / SCHUNK, 256, 0, stream>>>(
        ei, cursor, packed, NE);
    blocal_kernel<<<NBUCK, 256, 0, stream>>>(packed, base, row_ptr, ssrc);

    // Conversions
    cvt_x_kernel<<<12500, 256, 0, stream>>>(x, xb, (long long)NN * DD / 4);
    cvt_w_kernel<<<(3 * 128 * 256 + 128 * 128 + 255) / 256, 256, 0, stream>>>(
        Wl, Wr, W1f, Wcat, Wp1);

    const int n_strips = NN / 32;   // 3125

    const u16* hcur = xb;
    u16* hnext;
    for (int i = 0; i < 3; ++i) {
        hnext = (i == 0) ? bufA : ((hcur == bufA) ? bufB : bufA);
        layer_kernel<<<n_strips, 256, 0, stream>>>(
            hcur, row_ptr, ssrc, Wcat + (size_t)i * 128 * 256,
            bl + (size_t)i * DD, br + (size_t)i * DD, hnext, n_strips);
        hcur = hnext;
    }
    u16* p1out = (hcur == bufA) ? bufB : bufA;
    post1_kernel<<<n_strips, 256, 0, stream>>>(hcur, Wp1, b1, p1out, n_strips);
    post2_kernel<<<1024, 256, 0, stream>>>(p1out, W2, b2, outp, NN);
}

// Round 8
// 454.151 us; speedup vs baseline: 1.5373x; 1.5373x over previous
//
#include <hip/hip_runtime.h>
#include <hip/hip_bf16.h>
#include <cstdint>
#include <cstddef>

#define NN 100000
#define DD 128
#define NE 1600000
#define NPB 196                 // nodes per bucket
#define NBUCK 511               // ceil(NN / NPB)
#define BCAP 6144               // LDS staging capacity per bucket (lambda=3136)
#define SCHUNK 8192             // edges per block-chunk in bscatter

typedef short bf16x8 __attribute__((ext_vector_type(8)));
typedef float f32x4 __attribute__((ext_vector_type(4)));
typedef unsigned short u16;
typedef unsigned int u32;

__device__ inline float b2f(u16 u) {
    union { u32 i; float f; } c; c.i = ((u32)u) << 16; return c.f;
}
__device__ inline u16 f2b(float f) {
    __hip_bfloat16 h = __float2bfloat16(f);   // RNE
    return *reinterpret_cast<u16*>(&h);
}

// ---------------------------------------------------------------------------
// CSR build, bucketed counting sort (round-6 proven chain).
// ---------------------------------------------------------------------------
__global__ __launch_bounds__(256)
void bcount_kernel(const int* __restrict__ ei, int* __restrict__ bcnt,
                   int n_edges) {
    __shared__ int h[NBUCK];
    for (int i = threadIdx.x; i < NBUCK; i += 256) h[i] = 0;
    __syncthreads();
    int t0 = blockIdx.x * blockDim.x + threadIdx.x;
    int stride = gridDim.x * blockDim.x;
    for (int e = t0; e < n_edges; e += stride)
        atomicAdd(&h[ei[n_edges + e] / NPB], 1);
    __syncthreads();
    for (int i = threadIdx.x; i < NBUCK; i += 256)
        if (h[i]) atomicAdd(&bcnt[i], h[i]);
}

__global__ __launch_bounds__(512)
void bscan_kernel(const int* __restrict__ bcnt, int* __restrict__ base,
                  int* __restrict__ cursor) {
    __shared__ int tmp[512];
    int t = threadIdx.x;
    int v = (t < NBUCK) ? bcnt[t] : 0;
    tmp[t] = v;
    __syncthreads();
    for (int o = 1; o < 512; o <<= 1) {
        int u = (t >= o) ? tmp[t - o] : 0;
        __syncthreads();
        tmp[t] += u;
        __syncthreads();
    }
    int excl = tmp[t] - v;
    if (t < NBUCK) { base[t] = excl; cursor[t] = excl; }
    if (t == NBUCK - 1) base[NBUCK] = excl + v;
}

__global__ __launch_bounds__(256)
void bscatter_kernel(const int* __restrict__ ei, int* __restrict__ cursor,
                     u32* __restrict__ packed, int n_edges) {
    __shared__ int hist[NBUCK];
    const int tid = threadIdx.x;
    const int nchunks = (n_edges + SCHUNK - 1) / SCHUNK;
    for (int ch = blockIdx.x; ch < nchunks; ch += gridDim.x) {
        const int e0 = ch * SCHUNK;
        const int e1 = min(e0 + SCHUNK, n_edges);
        for (int i = tid; i < NBUCK; i += 256) hist[i] = 0;
        __syncthreads();
        for (int e = e0 + tid; e < e1; e += 256)
            atomicAdd(&hist[ei[n_edges + e] / NPB], 1);
        __syncthreads();
        for (int i = tid; i < NBUCK; i += 256) {
            int c = hist[i];
            hist[i] = (c > 0) ? atomicAdd(&cursor[i], c) : 0;
        }
        __syncthreads();
        for (int e = e0 + tid; e < e1; e += 256) {
            int s = ei[e];
            int d = ei[n_edges + e];
            int b = d / NPB;
            int ld = d - b * NPB;
            int pos = atomicAdd(&hist[b], 1);
            packed[pos] = ((u32)ld << 17) | (u32)s;
        }
        __syncthreads();
    }
}

__global__ __launch_bounds__(256)
void blocal_kernel(const u32* __restrict__ packed, const int* __restrict__ base,
                   int* __restrict__ row_ptr, int* __restrict__ ssrc) {
    __shared__ int out_s[BCAP];
    __shared__ int cur_s[NPB];
    __shared__ int excl_s[NPB];
    __shared__ int ws[4];
    __shared__ int wexc[4];

    const int b = blockIdx.x;
    const int tid = threadIdx.x;
    const int lane = tid & 63, wv = tid >> 6;
    const int beg = base[b], end = base[b + 1];
    const int cnt = end - beg;

    if (tid < NPB) cur_s[tid] = 0;
    __syncthreads();
    for (int i = tid; i < cnt; i += 256)
        atomicAdd(&cur_s[packed[beg + i] >> 17], 1);
    __syncthreads();

    int v = (tid < NPB) ? cur_s[tid] : 0;
    int inc = v;
    #pragma unroll
    for (int o = 1; o < 64; o <<= 1) {
        int u = __shfl_up(inc, o);
        if (lane >= o) inc += u;
    }
    if (lane == 63) ws[wv] = inc;
    __syncthreads();
    if (tid == 0) {
        int s = 0;
        #pragma unroll
        for (int k = 0; k < 4; ++k) { wexc[k] = s; s += ws[k]; }
    }
    __syncthreads();
    int excl = inc - v + wexc[wv];
    if (tid < NPB) { excl_s[tid] = excl; }
    int gnode = b * NPB + tid;
    if (tid < NPB && gnode < NN) row_ptr[gnode] = beg + excl;
    if (b == 0 && tid == 0) row_ptr[NN] = NE;
    __syncthreads();
    if (tid < NPB) cur_s[tid] = excl_s[tid];
    __syncthreads();

    if (cnt <= BCAP) {
        for (int i = tid; i < cnt; i += 256) {
            u32 p = packed[beg + i];
            int pos = atomicAdd(&cur_s[p >> 17], 1);
            out_s[pos] = (int)(p & 0x1FFFF);
        }
        __syncthreads();
        for (int i = tid; i < cnt; i += 256) ssrc[beg + i] = out_s[i];
    } else {
        for (int i = tid; i < cnt; i += 256) {
            u32 p = packed[beg + i];
            int pos = atomicAdd(&cur_s[p >> 17], 1);
            ssrc[beg + pos] = (int)(p & 0x1FFFF);
        }
    }
}

// ---------------------------------------------------------------------------
// Conversions
// ---------------------------------------------------------------------------
__global__ __launch_bounds__(256)
void cvt_x_kernel(const float* __restrict__ x, u16* __restrict__ xb, long long n4) {
    long long t = (long long)blockIdx.x * blockDim.x + threadIdx.x;
    long long stride = (long long)gridDim.x * blockDim.x;
    for (; t < n4; t += stride) {
        float4 v = reinterpret_cast<const float4*>(x)[t];
        ushort4 o;
        o.x = f2b(v.x); o.y = f2b(v.y); o.z = f2b(v.z); o.w = f2b(v.w);
        reinterpret_cast<ushort4*>(xb)[t] = o;
    }
}

__global__ __launch_bounds__(256)
void cvt_w_kernel(const float* __restrict__ Wl, const float* __restrict__ Wr,
                  const float* __restrict__ Wp1f, u16* __restrict__ Wcat,
                  u16* __restrict__ Wp1) {
    int t = blockIdx.x * blockDim.x + threadIdx.x;
    const int NCAT = 3 * 128 * 256;
    if (t < NCAT) {
        int layer = t >> 15;
        int rem = t & 32767;
        int d = rem >> 8;
        int k = rem & 255;
        float v = (k < 128) ? Wl[layer * 16384 + d * 128 + k]
                            : Wr[layer * 16384 + d * 128 + (k - 128)];
        Wcat[t] = f2b(v);
    } else if (t < NCAT + 128 * 128) {
        int i = t - NCAT;
        Wp1[i] = f2b(Wp1f[i]);
    }
}

// ---------------------------------------------------------------------------
// Gather aggregation v2: register-staged edge list + shfl broadcast.
// One wave per node; lane e pre-loads ssrc[beg+e] (one coalesced load covers
// deg<=64, ~4x the mean degree of 16); indices are then broadcast via __shfl
// so the h-row loads are the ONLY memory ops in the loop (unroll-4 in
// flight). Uniform-load tail handles deg>64 correctly (stat. negligible).
// ---------------------------------------------------------------------------
__global__ __launch_bounds__(256)
void gather_kernel(const u16* __restrict__ h, const int* __restrict__ rp,
                   const int* __restrict__ ssrc, u16* __restrict__ prop,
                   int n_nodes) {
    int wid = (blockIdx.x * blockDim.x + threadIdx.x) >> 6;
    int lane = threadIdx.x & 63;
    if (wid >= n_nodes) return;
    int beg = rp[wid], end = rp[wid + 1];
    int deg = end - beg;
    int nb = min(deg, 64);
    float ax = 0.0f, ay = 0.0f;
    const u16* hb = h + lane * 2;

    int sv = (lane < nb) ? ssrc[beg + lane] : 0;   // coalesced edge-index stage

    int j = 0;
    for (; j + 3 < nb; j += 4) {
        int s0 = __shfl(sv, j);
        int s1 = __shfl(sv, j + 1);
        int s2 = __shfl(sv, j + 2);
        int s3 = __shfl(sv, j + 3);
        u32 v0 = *reinterpret_cast<const u32*>(hb + (size_t)s0 * DD);
        u32 v1 = *reinterpret_cast<const u32*>(hb + (size_t)s1 * DD);
        u32 v2 = *reinterpret_cast<const u32*>(hb + (size_t)s2 * DD);
        u32 v3 = *reinterpret_cast<const u32*>(hb + (size_t)s3 * DD);
        union { u32 i; float f; } c;
        c.i = v0 << 16; ax += c.f;
        c.i = v0 & 0xffff0000u; ay += c.f;
        c.i = v1 << 16; ax += c.f;
        c.i = v1 & 0xffff0000u; ay += c.f;
        c.i = v2 << 16; ax += c.f;
        c.i = v2 & 0xffff0000u; ay += c.f;
        c.i = v3 << 16; ax += c.f;
        c.i = v3 & 0xffff0000u; ay += c.f;
    }
    for (; j < nb; ++j) {
        int s0 = __shfl(sv, j);
        u32 v0 = *reinterpret_cast<const u32*>(hb + (size_t)s0 * DD);
        union { u32 i; float f; } c;
        c.i = v0 << 16; ax += c.f;
        c.i = v0 & 0xffff0000u; ay += c.f;
    }
    // deg > 64 tail (rare): uniform loads
    for (int e = beg + 64; e < end; ++e) {
        u32 v0 = *reinterpret_cast<const u32*>(hb + (size_t)ssrc[e] * DD);
        union { u32 i; float f; } c;
        c.i = v0 << 16; ax += c.f;
        c.i = v0 & 0xffff0000u; ay += c.f;
    }

    u32 o = (u32)f2b(ax) | ((u32)f2b(ay) << 16);
    *reinterpret_cast<u32*>(prop + (size_t)wid * DD + lane * 2) = o;
}

// ---------------------------------------------------------------------------
// MFMA layer GEMM (round-6 proven).
//   KSTEPS=8, DUAL_NORM=true : out = normalize_relu([h|prop] @ Wcat^T + b)
//   KSTEPS=4, DUAL_NORM=false: out = h @ Wp1^T + b1
// ---------------------------------------------------------------------------
template<int KSTEPS, bool DUAL_NORM>
__global__ __launch_bounds__(256)
void mfma_layer(const u16* __restrict__ hin, const u16* __restrict__ prop,
                const u16* __restrict__ Wc, const float* __restrict__ b1,
                const float* __restrict__ b2, u16* __restrict__ out,
                int n_strips) {
    constexpr int ROWB = KSTEPS * 64;
    constexpr int CPR = KSTEPS * 4;
    constexpr int KTOT = KSTEPS * 32;
    __shared__ char a_s[32 * ROWB];
    __shared__ float red_s[32][4];

    const int tid = threadIdx.x;
    const int w = tid >> 6;
    const int l = tid & 63;
    const int q = l >> 4;
    const int c16 = l & 15;

    bf16x8 bfrag[2][KSTEPS];
    int col[2];
    float bias[2];
    #pragma unroll
    for (int t = 0; t < 2; ++t) {
        col[t] = w * 32 + t * 16 + c16;
        bias[t] = b1[col[t]] + (DUAL_NORM ? b2[col[t]] : 0.0f);
        #pragma unroll
        for (int kk = 0; kk < KSTEPS; ++kk)
            bfrag[t][kk] = *reinterpret_cast<const bf16x8*>(
                Wc + (size_t)col[t] * KTOT + kk * 32 + q * 8);
    }

    for (int strip = blockIdx.x; strip < n_strips; strip += gridDim.x) {
        const int base = strip * 32;

        for (int ci = tid; ci < 32 * CPR; ci += 256) {
            int r = ci / CPR, c = ci % CPR;
            const u16* src;
            int node = base + r;
            if (DUAL_NORM)
                src = (c < 16) ? (hin + (size_t)node * DD + c * 8)
                               : (prop + (size_t)node * DD + (c - 16) * 8);
            else
                src = hin + (size_t)node * DD + c * 8;
            *reinterpret_cast<uint4*>(a_s + r * ROWB + ((c ^ (r & 7)) * 16)) =
                *reinterpret_cast<const uint4*>(src);
        }
        __syncthreads();

        f32x4 acc[2][2] = {};
        #pragma unroll
        for (int kk = 0; kk < KSTEPS; ++kk) {
            int cc = kk * 4 + q;
            bf16x8 a0 = *reinterpret_cast<const bf16x8*>(
                a_s + c16 * ROWB + ((cc ^ (c16 & 7)) * 16));
            bf16x8 a1 = *reinterpret_cast<const bf16x8*>(
                a_s + (16 + c16) * ROWB + ((cc ^ ((16 + c16) & 7)) * 16));
            acc[0][0] = __builtin_amdgcn_mfma_f32_16x16x32_bf16(a0, bfrag[0][kk], acc[0][0], 0, 0, 0);
            acc[0][1] = __builtin_amdgcn_mfma_f32_16x16x32_bf16(a0, bfrag[1][kk], acc[0][1], 0, 0, 0);
            acc[1][0] = __builtin_amdgcn_mfma_f32_16x16x32_bf16(a1, bfrag[0][kk], acc[1][0], 0, 0, 0);
            acc[1][1] = __builtin_amdgcn_mfma_f32_16x16x32_bf16(a1, bfrag[1][kk], acc[1][1], 0, 0, 0);
        }

        if (DUAL_NORM) {
            float vals[2][2][4];
            float ss[2][4];
            #pragma unroll
            for (int m = 0; m < 2; ++m) {
                #pragma unroll
                for (int reg = 0; reg < 4; ++reg) {
                    float s = 0.0f;
                    #pragma unroll
                    for (int t = 0; t < 2; ++t) {
                        float v = acc[m][t][reg] + bias[t];
                        vals[m][t][reg] = v;
                        s += v * v;
                    }
                    s += __shfl_xor(s, 1);
                    s += __shfl_xor(s, 2);
                    s += __shfl_xor(s, 4);
                    s += __shfl_xor(s, 8);
                    ss[m][reg] = s;
                }
            }
            if (c16 == 0) {
                #pragma unroll
                for (int m = 0; m < 2; ++m)
                    #pragma unroll
                    for (int reg = 0; reg < 4; ++reg)
                        red_s[m * 16 + q * 4 + reg][w] = ss[m][reg];
            }
            __syncthreads();
            #pragma unroll
            for (int m = 0; m < 2; ++m) {
                #pragma unroll
                for (int reg = 0; reg < 4; ++reg) {
                    int row = m * 16 + q * 4 + reg;
                    float4 rr = *reinterpret_cast<float4*>(&red_s[row][0]);
                    float tot = rr.x + rr.y + rr.z + rr.w;
                    float rn = 1.0f / fmaxf(sqrtf(tot), 1e-12f);
                    #pragma unroll
                    for (int t = 0; t < 2; ++t) {
                        float v = fmaxf(vals[m][t][reg] * rn, 0.0f);
                        out[(size_t)(base + row) * DD + col[t]] = f2b(v);
                    }
                }
            }
            __syncthreads();
        } else {
            #pragma unroll
            for (int m = 0; m < 2; ++m)
                #pragma unroll
                for (int reg = 0; reg < 4; ++reg) {
                    int row = m * 16 + q * 4 + reg;
                    #pragma unroll
                    for (int t = 0; t < 2; ++t) {
                        float v = acc[m][t][reg] + bias[t];
                        out[(size_t)(base + row) * DD + col[t]] = f2b(v);
                    }
                }
            __syncthreads();
        }
    }
}

// ---------------------------------------------------------------------------
// Post2 + log_softmax (bf16 in, fp32 out)
// ---------------------------------------------------------------------------
__global__ __launch_bounds__(256)
void post2_kernel(const u16* __restrict__ hin, const float* __restrict__ W2,
                  const float* __restrict__ b2, float* __restrict__ out,
                  int n_nodes) {
    __shared__ float w_s[40 * 132];
    __shared__ float row_s[4][DD];
    const int tid = threadIdx.x;

    {
        const float4* gw = reinterpret_cast<const float4*>(W2);
        float4* sw = reinterpret_cast<float4*>(w_s);
        for (int j = tid; j < 40 * 32; j += 256) {
            int r = j >> 5, c = j & 31;
            sw[r * 33 + c] = gw[j];
        }
    }
    __syncthreads();

    const int wave = tid >> 6;
    const int lane = tid & 63;
    const float4* w4 = reinterpret_cast<const float4*>(w_s);
    const int lr = (lane < 40) ? lane : 0;
    const float bias = (lane < 40) ? b2[lr] : 0.0f;

    for (int base = blockIdx.x * 4; base < n_nodes; base += gridDim.x * 4) {
        int n = base + wave;
        bool alive = (n < n_nodes);
        if (alive) {
            row_s[wave][lane] = b2f(hin[(size_t)n * DD + lane]);
            row_s[wave][64 + lane] = b2f(hin[(size_t)n * DD + 64 + lane]);
        }
        __syncthreads();

        float acc = bias;
        const float4* r4 = reinterpret_cast<const float4*>(row_s[wave]);
        #pragma unroll
        for (int c = 0; c < 32; ++c) {
            float4 rv = r4[c];
            float4 wv = w4[lr * 33 + c];
            acc += rv.x * wv.x + rv.y * wv.y + rv.z * wv.z + rv.w * wv.w;
        }

        float m = (alive && lane < 40) ? acc : -INFINITY;
        #pragma unroll
        for (int o = 32; o > 0; o >>= 1) m = fmaxf(m, __shfl_xor(m, o));
        float e = (alive && lane < 40) ? expf(acc - m) : 0.0f;
        #pragma unroll
        for (int o = 32; o > 0; o >>= 1) e += __shfl_xor(e, o);

        if (alive && lane < 40) out[(size_t)n * 40 + lane] = acc - m - logf(e);
        __syncthreads();
    }
}

// ---------------------------------------------------------------------------
extern "C" void kernel_launch(void* const* d_in, const int* in_sizes, int n_in,
                              void* d_out, int out_size, void* d_ws, size_t ws_size,
                              hipStream_t stream) {
    const float* x   = (const float*)d_in[0];
    const int*   ei  = (const int*)d_in[1];
    const float* Wl  = (const float*)d_in[2];
    const float* bl  = (const float*)d_in[3];
    const float* Wr  = (const float*)d_in[4];
    const float* br  = (const float*)d_in[5];
    const float* W1f = (const float*)d_in[6];
    const float* b1  = (const float*)d_in[7];
    const float* W2  = (const float*)d_in[8];
    const float* b2  = (const float*)d_in[9];
    float* outp = (float*)d_out;

    // Workspace: xb | P | bufA | bufB | Wcat | Wp1 | bcnt | base | cursor |
    //            row_ptr | ssrc | packed
    u16* xb   = (u16*)d_ws;
    u16* P    = xb + (size_t)NN * DD;
    u16* bufA = P + (size_t)NN * DD;
    u16* bufB = bufA + (size_t)NN * DD;
    u16* Wcat = bufB + (size_t)NN * DD;
    u16* Wp1  = Wcat + 3 * 128 * 256;
    int* bcnt    = (int*)(Wp1 + 128 * 128);
    int* base    = bcnt + NBUCK + 1;
    int* cursor  = base + NBUCK + 1;
    int* row_ptr = cursor + NBUCK + 1;
    int* ssrc    = row_ptr + NN + 1;
    u32* packed  = (u32*)(ssrc + NE);

    // CSR build (bucketed counting sort, chunk-reserved scatter)
    hipMemsetAsync(bcnt, 0, (NBUCK + 1) * sizeof(int), stream);
    bcount_kernel<<<128, 256, 0, stream>>>(ei, bcnt, NE);
    bscan_kernel<<<1, 512, 0, stream>>>(bcnt, base, cursor);
    bscatter_kernel<<<(NE + SCHUNK - 1) / SCHUNK, 256, 0, stream>>>(
        ei, cursor, packed, NE);
    blocal_kernel<<<NBUCK, 256, 0, stream>>>(packed, base, row_ptr, ssrc);

    // Conversions
    cvt_x_kernel<<<12500, 256, 0, stream>>>(x, xb, (long long)NN * DD / 4);
    cvt_w_kernel<<<(3 * 128 * 256 + 128 * 128 + 255) / 256, 256, 0, stream>>>(
        Wl, Wr, W1f, Wcat, Wp1);

    const int n_strips = NN / 32;   // 3125
    const int gather_grid = (NN * 64 + 255) / 256;

    const u16* hcur = xb;
    u16* hnext;
    for (int i = 0; i < 3; ++i) {
        hnext = (i == 0) ? bufA : ((hcur == bufA) ? bufB : bufA);
        gather_kernel<<<gather_grid, 256, 0, stream>>>(hcur, row_ptr, ssrc, P, NN);
        mfma_layer<8, true><<<n_strips, 256, 0, stream>>>(
            hcur, P, Wcat + (size_t)i * 128 * 256,
            bl + (size_t)i * DD, br + (size_t)i * DD, hnext, n_strips);
        hcur = hnext;
    }
    u16* p1out = (hcur == bufA) ? bufB : bufA;
    mfma_layer<4, false><<<n_strips, 256, 0, stream>>>(
        hcur, nullptr, Wp1, b1, nullptr, p1out, n_strips);
    post2_kernel<<<1024, 256, 0, stream>>>(p1out, W2, b2, outp, NN);
}

// Round 9
// 386.580 us; speedup vs baseline: 1.8060x; 1.1748x over previous
//
#include <hip/hip_runtime.h>
#include <hip/hip_bf16.h>
#include <cstdint>
#include <cstddef>

#define NN 100000
#define DD 128
#define NE 1600000
#define NPB 196                 // nodes per bucket
#define NBUCK 511               // ceil(NN / NPB)
#define BCAP 6144               // LDS staging capacity per bucket (lambda=3136)
#define SCHUNK 8192             // edges per block-chunk in bscatter

typedef short bf16x8 __attribute__((ext_vector_type(8)));
typedef float f32x4 __attribute__((ext_vector_type(4)));
typedef unsigned short u16;
typedef unsigned int u32;

__device__ inline float b2f(u16 u) {
    union { u32 i; float f; } c; c.i = ((u32)u) << 16; return c.f;
}
__device__ inline u16 f2b(float f) {
    __hip_bfloat16 h = __float2bfloat16(f);   // RNE
    return *reinterpret_cast<u16*>(&h);
}

// ---------------------------------------------------------------------------
// CSR build, bucketed counting sort (round-6 proven chain).
// ---------------------------------------------------------------------------
__global__ __launch_bounds__(256)
void bcount_kernel(const int* __restrict__ ei, int* __restrict__ bcnt,
                   int n_edges) {
    __shared__ int h[NBUCK];
    for (int i = threadIdx.x; i < NBUCK; i += 256) h[i] = 0;
    __syncthreads();
    int t0 = blockIdx.x * blockDim.x + threadIdx.x;
    int stride = gridDim.x * blockDim.x;
    for (int e = t0; e < n_edges; e += stride)
        atomicAdd(&h[ei[n_edges + e] / NPB], 1);
    __syncthreads();
    for (int i = threadIdx.x; i < NBUCK; i += 256)
        if (h[i]) atomicAdd(&bcnt[i], h[i]);
}

__global__ __launch_bounds__(512)
void bscan_kernel(const int* __restrict__ bcnt, int* __restrict__ base,
                  int* __restrict__ cursor) {
    __shared__ int tmp[512];
    int t = threadIdx.x;
    int v = (t < NBUCK) ? bcnt[t] : 0;
    tmp[t] = v;
    __syncthreads();
    for (int o = 1; o < 512; o <<= 1) {
        int u = (t >= o) ? tmp[t - o] : 0;
        __syncthreads();
        tmp[t] += u;
        __syncthreads();
    }
    int excl = tmp[t] - v;
    if (t < NBUCK) { base[t] = excl; cursor[t] = excl; }
    if (t == NBUCK - 1) base[NBUCK] = excl + v;
}

__global__ __launch_bounds__(256)
void bscatter_kernel(const int* __restrict__ ei, int* __restrict__ cursor,
                     u32* __restrict__ packed, int n_edges) {
    __shared__ int hist[NBUCK];
    const int tid = threadIdx.x;
    const int nchunks = (n_edges + SCHUNK - 1) / SCHUNK;
    for (int ch = blockIdx.x; ch < nchunks; ch += gridDim.x) {
        const int e0 = ch * SCHUNK;
        const int e1 = min(e0 + SCHUNK, n_edges);
        for (int i = tid; i < NBUCK; i += 256) hist[i] = 0;
        __syncthreads();
        for (int e = e0 + tid; e < e1; e += 256)
            atomicAdd(&hist[ei[n_edges + e] / NPB], 1);
        __syncthreads();
        for (int i = tid; i < NBUCK; i += 256) {
            int c = hist[i];
            hist[i] = (c > 0) ? atomicAdd(&cursor[i], c) : 0;
        }
        __syncthreads();
        for (int e = e0 + tid; e < e1; e += 256) {
            int s = ei[e];
            int d = ei[n_edges + e];
            int b = d / NPB;
            int ld = d - b * NPB;
            int pos = atomicAdd(&hist[b], 1);
            packed[pos] = ((u32)ld << 17) | (u32)s;
        }
        __syncthreads();
    }
}

__global__ __launch_bounds__(256)
void blocal_kernel(const u32* __restrict__ packed, const int* __restrict__ base,
                   int* __restrict__ row_ptr, int* __restrict__ ssrc) {
    __shared__ int out_s[BCAP];
    __shared__ int cur_s[NPB];
    __shared__ int excl_s[NPB];
    __shared__ int ws[4];
    __shared__ int wexc[4];

    const int b = blockIdx.x;
    const int tid = threadIdx.x;
    const int lane = tid & 63, wv = tid >> 6;
    const int beg = base[b], end = base[b + 1];
    const int cnt = end - beg;

    if (tid < NPB) cur_s[tid] = 0;
    __syncthreads();
    for (int i = tid; i < cnt; i += 256)
        atomicAdd(&cur_s[packed[beg + i] >> 17], 1);
    __syncthreads();

    int v = (tid < NPB) ? cur_s[tid] : 0;
    int inc = v;
    #pragma unroll
    for (int o = 1; o < 64; o <<= 1) {
        int u = __shfl_up(inc, o);
        if (lane >= o) inc += u;
    }
    if (lane == 63) ws[wv] = inc;
    __syncthreads();
    if (tid == 0) {
        int s = 0;
        #pragma unroll
        for (int k = 0; k < 4; ++k) { wexc[k] = s; s += ws[k]; }
    }
    __syncthreads();
    int excl = inc - v + wexc[wv];
    if (tid < NPB) { excl_s[tid] = excl; }
    int gnode = b * NPB + tid;
    if (tid < NPB && gnode < NN) row_ptr[gnode] = beg + excl;
    if (b == 0 && tid == 0) row_ptr[NN] = NE;
    __syncthreads();
    if (tid < NPB) cur_s[tid] = excl_s[tid];
    __syncthreads();

    if (cnt <= BCAP) {
        for (int i = tid; i < cnt; i += 256) {
            u32 p = packed[beg + i];
            int pos = atomicAdd(&cur_s[p >> 17], 1);
            out_s[pos] = (int)(p & 0x1FFFF);
        }
        __syncthreads();
        for (int i = tid; i < cnt; i += 256) ssrc[beg + i] = out_s[i];
    } else {
        for (int i = tid; i < cnt; i += 256) {
            u32 p = packed[beg + i];
            int pos = atomicAdd(&cur_s[p >> 17], 1);
            ssrc[beg + pos] = (int)(p & 0x1FFFF);
        }
    }
}

// ---------------------------------------------------------------------------
// Conversions
// ---------------------------------------------------------------------------
__global__ __launch_bounds__(256)
void cvt_x_kernel(const float* __restrict__ x, u16* __restrict__ xb, long long n4) {
    long long t = (long long)blockIdx.x * blockDim.x + threadIdx.x;
    long long stride = (long long)gridDim.x * blockDim.x;
    for (; t < n4; t += stride) {
        float4 v = reinterpret_cast<const float4*>(x)[t];
        ushort4 o;
        o.x = f2b(v.x); o.y = f2b(v.y); o.z = f2b(v.z); o.w = f2b(v.w);
        reinterpret_cast<ushort4*>(xb)[t] = o;
    }
}

// Wcat[l][d][k] (k<128 from Wl, else Wr) in bf16.
__global__ __launch_bounds__(256)
void cvt_w_kernel(const float* __restrict__ Wl, const float* __restrict__ Wr,
                  u16* __restrict__ Wcat) {
    int t = blockIdx.x * blockDim.x + threadIdx.x;
    const int NCAT = 3 * 128 * 256;
    if (t < NCAT) {
        int layer = t >> 15;
        int rem = t & 32767;
        int d = rem >> 8;
        int k = rem & 255;
        float v = (k < 128) ? Wl[layer * 16384 + d * 128 + k]
                            : Wr[layer * 16384 + d * 128 + (k - 128)];
        Wcat[t] = f2b(v);
    }
}

// Algebraic post-fusion: Wfuse = W_post2 @ W_post1 (40x128, bf16, padded to
// 48 cols), bfuse = W_post2 @ b_post1 + b_post2 (fp32).
__global__ __launch_bounds__(256)
void wfuse_kernel(const float* __restrict__ W1f, const float* __restrict__ b1,
                  const float* __restrict__ W2, const float* __restrict__ b2,
                  u16* __restrict__ Wfb, float* __restrict__ bfuse) {
    int t = blockIdx.x * 256 + threadIdx.x;
    if (t < 48 * 128) {
        int l = t >> 7, k = t & 127;
        float s = 0.0f;
        if (l < 40) {
            for (int j = 0; j < 128; ++j)
                s += W2[l * 128 + j] * W1f[j * 128 + k];
        }
        Wfb[t] = f2b(s);
    }
    if (blockIdx.x == 0 && threadIdx.x < 40) {
        int l = threadIdx.x;
        float s = b2[l];
        for (int j = 0; j < 128; ++j) s += W2[l * 128 + j] * b1[j];
        bfuse[l] = s;
    }
}

// ---------------------------------------------------------------------------
// Gather aggregation v2 (round-8 proven): register-staged edge list + shfl.
// ---------------------------------------------------------------------------
__global__ __launch_bounds__(256)
void gather_kernel(const u16* __restrict__ h, const int* __restrict__ rp,
                   const int* __restrict__ ssrc, u16* __restrict__ prop,
                   int n_nodes) {
    int wid = (blockIdx.x * blockDim.x + threadIdx.x) >> 6;
    int lane = threadIdx.x & 63;
    if (wid >= n_nodes) return;
    int beg = rp[wid], end = rp[wid + 1];
    int deg = end - beg;
    int nb = min(deg, 64);
    float ax = 0.0f, ay = 0.0f;
    const u16* hb = h + lane * 2;

    int sv = (lane < nb) ? ssrc[beg + lane] : 0;

    int j = 0;
    for (; j + 3 < nb; j += 4) {
        int s0 = __shfl(sv, j);
        int s1 = __shfl(sv, j + 1);
        int s2 = __shfl(sv, j + 2);
        int s3 = __shfl(sv, j + 3);
        u32 v0 = *reinterpret_cast<const u32*>(hb + (size_t)s0 * DD);
        u32 v1 = *reinterpret_cast<const u32*>(hb + (size_t)s1 * DD);
        u32 v2 = *reinterpret_cast<const u32*>(hb + (size_t)s2 * DD);
        u32 v3 = *reinterpret_cast<const u32*>(hb + (size_t)s3 * DD);
        union { u32 i; float f; } c;
        c.i = v0 << 16; ax += c.f;
        c.i = v0 & 0xffff0000u; ay += c.f;
        c.i = v1 << 16; ax += c.f;
        c.i = v1 & 0xffff0000u; ay += c.f;
        c.i = v2 << 16; ax += c.f;
        c.i = v2 & 0xffff0000u; ay += c.f;
        c.i = v3 << 16; ax += c.f;
        c.i = v3 & 0xffff0000u; ay += c.f;
    }
    for (; j < nb; ++j) {
        int s0 = __shfl(sv, j);
        u32 v0 = *reinterpret_cast<const u32*>(hb + (size_t)s0 * DD);
        union { u32 i; float f; } c;
        c.i = v0 << 16; ax += c.f;
        c.i = v0 & 0xffff0000u; ay += c.f;
    }
    for (int e = beg + 64; e < end; ++e) {
        u32 v0 = *reinterpret_cast<const u32*>(hb + (size_t)ssrc[e] * DD);
        union { u32 i; float f; } c;
        c.i = v0 << 16; ax += c.f;
        c.i = v0 & 0xffff0000u; ay += c.f;
    }

    u32 o = (u32)f2b(ax) | ((u32)f2b(ay) << 16);
    *reinterpret_cast<u32*>(prop + (size_t)wid * DD + lane * 2) = o;
}

// ---------------------------------------------------------------------------
// MFMA layer GEMM (round-6 proven): [h|prop] @ Wcat^T + b -> norm -> ReLU.
// ---------------------------------------------------------------------------
template<int KSTEPS, bool DUAL_NORM>
__global__ __launch_bounds__(256)
void mfma_layer(const u16* __restrict__ hin, const u16* __restrict__ prop,
                const u16* __restrict__ Wc, const float* __restrict__ b1,
                const float* __restrict__ b2, u16* __restrict__ out,
                int n_strips) {
    constexpr int ROWB = KSTEPS * 64;
    constexpr int CPR = KSTEPS * 4;
    constexpr int KTOT = KSTEPS * 32;
    __shared__ char a_s[32 * ROWB];
    __shared__ float red_s[32][4];

    const int tid = threadIdx.x;
    const int w = tid >> 6;
    const int l = tid & 63;
    const int q = l >> 4;
    const int c16 = l & 15;

    bf16x8 bfrag[2][KSTEPS];
    int col[2];
    float bias[2];
    #pragma unroll
    for (int t = 0; t < 2; ++t) {
        col[t] = w * 32 + t * 16 + c16;
        bias[t] = b1[col[t]] + (DUAL_NORM ? b2[col[t]] : 0.0f);
        #pragma unroll
        for (int kk = 0; kk < KSTEPS; ++kk)
            bfrag[t][kk] = *reinterpret_cast<const bf16x8*>(
                Wc + (size_t)col[t] * KTOT + kk * 32 + q * 8);
    }

    for (int strip = blockIdx.x; strip < n_strips; strip += gridDim.x) {
        const int base = strip * 32;

        for (int ci = tid; ci < 32 * CPR; ci += 256) {
            int r = ci / CPR, c = ci % CPR;
            const u16* src;
            int node = base + r;
            if (DUAL_NORM)
                src = (c < 16) ? (hin + (size_t)node * DD + c * 8)
                               : (prop + (size_t)node * DD + (c - 16) * 8);
            else
                src = hin + (size_t)node * DD + c * 8;
            *reinterpret_cast<uint4*>(a_s + r * ROWB + ((c ^ (r & 7)) * 16)) =
                *reinterpret_cast<const uint4*>(src);
        }
        __syncthreads();

        f32x4 acc[2][2] = {};
        #pragma unroll
        for (int kk = 0; kk < KSTEPS; ++kk) {
            int cc = kk * 4 + q;
            bf16x8 a0 = *reinterpret_cast<const bf16x8*>(
                a_s + c16 * ROWB + ((cc ^ (c16 & 7)) * 16));
            bf16x8 a1 = *reinterpret_cast<const bf16x8*>(
                a_s + (16 + c16) * ROWB + ((cc ^ ((16 + c16) & 7)) * 16));
            acc[0][0] = __builtin_amdgcn_mfma_f32_16x16x32_bf16(a0, bfrag[0][kk], acc[0][0], 0, 0, 0);
            acc[0][1] = __builtin_amdgcn_mfma_f32_16x16x32_bf16(a0, bfrag[1][kk], acc[0][1], 0, 0, 0);
            acc[1][0] = __builtin_amdgcn_mfma_f32_16x16x32_bf16(a1, bfrag[0][kk], acc[1][0], 0, 0, 0);
            acc[1][1] = __builtin_amdgcn_mfma_f32_16x16x32_bf16(a1, bfrag[1][kk], acc[1][1], 0, 0, 0);
        }

        if (DUAL_NORM) {
            float vals[2][2][4];
            float ss[2][4];
            #pragma unroll
            for (int m = 0; m < 2; ++m) {
                #pragma unroll
                for (int reg = 0; reg < 4; ++reg) {
                    float s = 0.0f;
                    #pragma unroll
                    for (int t = 0; t < 2; ++t) {
                        float v = acc[m][t][reg] + bias[t];
                        vals[m][t][reg] = v;
                        s += v * v;
                    }
                    s += __shfl_xor(s, 1);
                    s += __shfl_xor(s, 2);
                    s += __shfl_xor(s, 4);
                    s += __shfl_xor(s, 8);
                    ss[m][reg] = s;
                }
            }
            if (c16 == 0) {
                #pragma unroll
                for (int m = 0; m < 2; ++m)
                    #pragma unroll
                    for (int reg = 0; reg < 4; ++reg)
                        red_s[m * 16 + q * 4 + reg][w] = ss[m][reg];
            }
            __syncthreads();
            #pragma unroll
            for (int m = 0; m < 2; ++m) {
                #pragma unroll
                for (int reg = 0; reg < 4; ++reg) {
                    int row = m * 16 + q * 4 + reg;
                    float4 rr = *reinterpret_cast<float4*>(&red_s[row][0]);
                    float tot = rr.x + rr.y + rr.z + rr.w;
                    float rn = 1.0f / fmaxf(sqrtf(tot), 1e-12f);
                    #pragma unroll
                    for (int t = 0; t < 2; ++t) {
                        float v = fmaxf(vals[m][t][reg] * rn, 0.0f);
                        out[(size_t)(base + row) * DD + col[t]] = f2b(v);
                    }
                }
            }
            __syncthreads();
        } else {
            #pragma unroll
            for (int m = 0; m < 2; ++m)
                #pragma unroll
                for (int reg = 0; reg < 4; ++reg) {
                    int row = m * 16 + q * 4 + reg;
                    #pragma unroll
                    for (int t = 0; t < 2; ++t) {
                        float v = acc[m][t][reg] + bias[t];
                        out[(size_t)(base + row) * DD + col[t]] = f2b(v);
                    }
                }
            __syncthreads();
        }
    }
}

// ---------------------------------------------------------------------------
// Fused post stage: out = log_softmax(h @ Wfuse^T + bfuse), 40 classes.
// 64-node strips; wave w owns rows w*16..+15; 3 col-tiles (48 incl. 8 pad);
// per-row reduce across the 16-lane c16 group.
// ---------------------------------------------------------------------------
__global__ __launch_bounds__(256)
void postfused_kernel(const u16* __restrict__ hin, const u16* __restrict__ Wfb,
                      const float* __restrict__ bfuse, float* __restrict__ out,
                      int n_nodes) {
    __shared__ char a_s[64 * 256];
    const int tid = threadIdx.x;
    const int w = tid >> 6;
    const int l = tid & 63;
    const int q = l >> 4;
    const int c16 = l & 15;

    bf16x8 bfrag[3][4];
    float bias[3];
    int col[3];
    #pragma unroll
    for (int t = 0; t < 3; ++t) {
        col[t] = t * 16 + c16;
        bias[t] = (col[t] < 40) ? bfuse[col[t]] : 0.0f;
        #pragma unroll
        for (int kk = 0; kk < 4; ++kk)
            bfrag[t][kk] = *reinterpret_cast<const bf16x8*>(
                Wfb + col[t] * 128 + kk * 32 + q * 8);
    }

    const int base = blockIdx.x * 64;

    for (int ci = tid; ci < 1024; ci += 256) {
        int r = ci >> 4, c = ci & 15;
        uint4 v = {0, 0, 0, 0};
        if (base + r < n_nodes)
            v = *reinterpret_cast<const uint4*>(hin + (size_t)(base + r) * DD + c * 8);
        *reinterpret_cast<uint4*>(a_s + r * 256 + ((c ^ (r & 7)) * 16)) = v;
    }
    __syncthreads();

    f32x4 acc[3] = {};
    const int arow = w * 16 + c16;
    #pragma unroll
    for (int kk = 0; kk < 4; ++kk) {
        int cc = kk * 4 + q;
        bf16x8 a = *reinterpret_cast<const bf16x8*>(
            a_s + arow * 256 + ((cc ^ (arow & 7)) * 16));
        acc[0] = __builtin_amdgcn_mfma_f32_16x16x32_bf16(a, bfrag[0][kk], acc[0], 0, 0, 0);
        acc[1] = __builtin_amdgcn_mfma_f32_16x16x32_bf16(a, bfrag[1][kk], acc[1], 0, 0, 0);
        acc[2] = __builtin_amdgcn_mfma_f32_16x16x32_bf16(a, bfrag[2][kk], acc[2], 0, 0, 0);
    }

    #pragma unroll
    for (int reg = 0; reg < 4; ++reg) {
        int row = base + w * 16 + q * 4 + reg;
        float v[3];
        float m = -INFINITY;
        #pragma unroll
        for (int t = 0; t < 3; ++t) {
            v[t] = acc[t][reg] + bias[t];
            if (col[t] < 40) m = fmaxf(m, v[t]);
        }
        m = fmaxf(m, __shfl_xor(m, 1));
        m = fmaxf(m, __shfl_xor(m, 2));
        m = fmaxf(m, __shfl_xor(m, 4));
        m = fmaxf(m, __shfl_xor(m, 8));
        float s = 0.0f;
        #pragma unroll
        for (int t = 0; t < 3; ++t)
            if (col[t] < 40) s += expf(v[t] - m);
        s += __shfl_xor(s, 1);
        s += __shfl_xor(s, 2);
        s += __shfl_xor(s, 4);
        s += __shfl_xor(s, 8);
        float lg = logf(s);
        if (row < n_nodes) {
            #pragma unroll
            for (int t = 0; t < 3; ++t)
                if (col[t] < 40)
                    out[(size_t)row * 40 + col[t]] = v[t] - m - lg;
        }
    }
}

// ---------------------------------------------------------------------------
extern "C" void kernel_launch(void* const* d_in, const int* in_sizes, int n_in,
                              void* d_out, int out_size, void* d_ws, size_t ws_size,
                              hipStream_t stream) {
    const float* x   = (const float*)d_in[0];
    const int*   ei  = (const int*)d_in[1];
    const float* Wl  = (const float*)d_in[2];
    const float* bl  = (const float*)d_in[3];
    const float* Wr  = (const float*)d_in[4];
    const float* br  = (const float*)d_in[5];
    const float* W1f = (const float*)d_in[6];
    const float* b1  = (const float*)d_in[7];
    const float* W2  = (const float*)d_in[8];
    const float* b2  = (const float*)d_in[9];
    float* outp = (float*)d_out;

    // Workspace: xb | P | bufA | bufB | Wcat | Wfb+bfuse | bcnt | base |
    //            cursor | row_ptr | ssrc | packed
    u16* xb   = (u16*)d_ws;
    u16* P    = xb + (size_t)NN * DD;
    u16* bufA = P + (size_t)NN * DD;
    u16* bufB = bufA + (size_t)NN * DD;
    u16* Wcat = bufB + (size_t)NN * DD;
    u16* Wfb  = Wcat + 3 * 128 * 256;          // 48*128 used of 128*128 slot
    float* bfuse = (float*)(Wfb + 8192);       // 40 floats, within the slot
    int* bcnt    = (int*)(Wfb + 128 * 128);
    int* base    = bcnt + NBUCK + 1;
    int* cursor  = base + NBUCK + 1;
    int* row_ptr = cursor + NBUCK + 1;
    int* ssrc    = row_ptr + NN + 1;
    u32* packed  = (u32*)(ssrc + NE);

    // CSR build (bucketed counting sort, chunk-reserved scatter)
    hipMemsetAsync(bcnt, 0, (NBUCK + 1) * sizeof(int), stream);
    bcount_kernel<<<128, 256, 0, stream>>>(ei, bcnt, NE);
    bscan_kernel<<<1, 512, 0, stream>>>(bcnt, base, cursor);
    bscatter_kernel<<<(NE + SCHUNK - 1) / SCHUNK, 256, 0, stream>>>(
        ei, cursor, packed, NE);
    blocal_kernel<<<NBUCK, 256, 0, stream>>>(packed, base, row_ptr, ssrc);

    // Conversions + algebraic post-fusion precompute
    cvt_x_kernel<<<12500, 256, 0, stream>>>(x, xb, (long long)NN * DD / 4);
    cvt_w_kernel<<<(3 * 128 * 256 + 255) / 256, 256, 0, stream>>>(Wl, Wr, Wcat);
    wfuse_kernel<<<24, 256, 0, stream>>>(W1f, b1, W2, b2, Wfb, bfuse);

    const int n_strips = NN / 32;   // 3125
    const int gather_grid = (NN * 64 + 255) / 256;

    const u16* hcur = xb;
    u16* hnext;
    for (int i = 0; i < 3; ++i) {
        hnext = (i == 0) ? bufA : ((hcur == bufA) ? bufB : bufA);
        gather_kernel<<<gather_grid, 256, 0, stream>>>(hcur, row_ptr, ssrc, P, NN);
        mfma_layer<8, true><<<n_strips, 256, 0, stream>>>(
            hcur, P, Wcat + (size_t)i * 128 * 256,
            bl + (size_t)i * DD, br + (size_t)i * DD, hnext, n_strips);
        hcur = hnext;
    }
    // Fused post1+post2+log_softmax
    postfused_kernel<<<(NN + 63) / 64, 256, 0, stream>>>(hcur, Wfb, bfuse, outp, NN);
}

// Round 10
// 359.912 us; speedup vs baseline: 1.9398x; 1.0741x over previous
//
#include <hip/hip_runtime.h>
#include <hip/hip_bf16.h>
#include <cstdint>
#include <cstddef>

#define NN 100000
#define DD 128
#define NE 1600000
#define NPB 196                 // nodes per bucket
#define NBUCK 511               // ceil(NN / NPB)
#define BCAP 6144               // LDS staging capacity per bucket (lambda=3136)
#define SCHUNK 8192             // edges per block-chunk in bscatter

typedef short bf16x8 __attribute__((ext_vector_type(8)));
typedef float f32x4 __attribute__((ext_vector_type(4)));
typedef unsigned short u16;
typedef unsigned int u32;

__device__ inline float b2f(u16 u) {
    union { u32 i; float f; } c; c.i = ((u32)u) << 16; return c.f;
}
__device__ inline u16 f2b(float f) {
    __hip_bfloat16 h = __float2bfloat16(f);   // RNE
    return *reinterpret_cast<u16*>(&h);
}

// ---------------------------------------------------------------------------
// CSR build, bucketed counting sort (round-6 proven chain).
// ---------------------------------------------------------------------------
__global__ __launch_bounds__(256)
void bcount_kernel(const int* __restrict__ ei, int* __restrict__ bcnt,
                   int n_edges) {
    __shared__ int h[NBUCK];
    for (int i = threadIdx.x; i < NBUCK; i += 256) h[i] = 0;
    __syncthreads();
    int t0 = blockIdx.x * blockDim.x + threadIdx.x;
    int stride = gridDim.x * blockDim.x;
    for (int e = t0; e < n_edges; e += stride)
        atomicAdd(&h[ei[n_edges + e] / NPB], 1);
    __syncthreads();
    for (int i = threadIdx.x; i < NBUCK; i += 256)
        if (h[i]) atomicAdd(&bcnt[i], h[i]);
}

__global__ __launch_bounds__(512)
void bscan_kernel(const int* __restrict__ bcnt, int* __restrict__ base,
                  int* __restrict__ cursor) {
    __shared__ int tmp[512];
    int t = threadIdx.x;
    int v = (t < NBUCK) ? bcnt[t] : 0;
    tmp[t] = v;
    __syncthreads();
    for (int o = 1; o < 512; o <<= 1) {
        int u = (t >= o) ? tmp[t - o] : 0;
        __syncthreads();
        tmp[t] += u;
        __syncthreads();
    }
    int excl = tmp[t] - v;
    if (t < NBUCK) { base[t] = excl; cursor[t] = excl; }
    if (t == NBUCK - 1) base[NBUCK] = excl + v;
}

__global__ __launch_bounds__(256)
void bscatter_kernel(const int* __restrict__ ei, int* __restrict__ cursor,
                     u32* __restrict__ packed, int n_edges) {
    __shared__ int hist[NBUCK];
    const int tid = threadIdx.x;
    const int nchunks = (n_edges + SCHUNK - 1) / SCHUNK;
    for (int ch = blockIdx.x; ch < nchunks; ch += gridDim.x) {
        const int e0 = ch * SCHUNK;
        const int e1 = min(e0 + SCHUNK, n_edges);
        for (int i = tid; i < NBUCK; i += 256) hist[i] = 0;
        __syncthreads();
        for (int e = e0 + tid; e < e1; e += 256)
            atomicAdd(&hist[ei[n_edges + e] / NPB], 1);
        __syncthreads();
        for (int i = tid; i < NBUCK; i += 256) {
            int c = hist[i];
            hist[i] = (c > 0) ? atomicAdd(&cursor[i], c) : 0;
        }
        __syncthreads();
        for (int e = e0 + tid; e < e1; e += 256) {
            int s = ei[e];
            int d = ei[n_edges + e];
            int b = d / NPB;
            int ld = d - b * NPB;
            int pos = atomicAdd(&hist[b], 1);
            packed[pos] = ((u32)ld << 17) | (u32)s;
        }
        __syncthreads();
    }
}

__global__ __launch_bounds__(256)
void blocal_kernel(const u32* __restrict__ packed, const int* __restrict__ base,
                   int* __restrict__ row_ptr, int* __restrict__ ssrc) {
    __shared__ int out_s[BCAP];
    __shared__ int cur_s[NPB];
    __shared__ int excl_s[NPB];
    __shared__ int ws[4];
    __shared__ int wexc[4];

    const int b = blockIdx.x;
    const int tid = threadIdx.x;
    const int lane = tid & 63, wv = tid >> 6;
    const int beg = base[b], end = base[b + 1];
    const int cnt = end - beg;

    if (tid < NPB) cur_s[tid] = 0;
    __syncthreads();
    for (int i = tid; i < cnt; i += 256)
        atomicAdd(&cur_s[packed[beg + i] >> 17], 1);
    __syncthreads();

    int v = (tid < NPB) ? cur_s[tid] : 0;
    int inc = v;
    #pragma unroll
    for (int o = 1; o < 64; o <<= 1) {
        int u = __shfl_up(inc, o);
        if (lane >= o) inc += u;
    }
    if (lane == 63) ws[wv] = inc;
    __syncthreads();
    if (tid == 0) {
        int s = 0;
        #pragma unroll
        for (int k = 0; k < 4; ++k) { wexc[k] = s; s += ws[k]; }
    }
    __syncthreads();
    int excl = inc - v + wexc[wv];
    if (tid < NPB) { excl_s[tid] = excl; }
    int gnode = b * NPB + tid;
    if (tid < NPB && gnode < NN) row_ptr[gnode] = beg + excl;
    if (b == 0 && tid == 0) row_ptr[NN] = NE;
    __syncthreads();
    if (tid < NPB) cur_s[tid] = excl_s[tid];
    __syncthreads();

    if (cnt <= BCAP) {
        for (int i = tid; i < cnt; i += 256) {
            u32 p = packed[beg + i];
            int pos = atomicAdd(&cur_s[p >> 17], 1);
            out_s[pos] = (int)(p & 0x1FFFF);
        }
        __syncthreads();
        for (int i = tid; i < cnt; i += 256) ssrc[beg + i] = out_s[i];
    } else {
        for (int i = tid; i < cnt; i += 256) {
            u32 p = packed[beg + i];
            int pos = atomicAdd(&cur_s[p >> 17], 1);
            ssrc[beg + pos] = (int)(p & 0x1FFFF);
        }
    }
}

// ---------------------------------------------------------------------------
// Conversions
// ---------------------------------------------------------------------------
__global__ __launch_bounds__(256)
void cvt_x_kernel(const float* __restrict__ x, u16* __restrict__ xb, long long n4) {
    long long t = (long long)blockIdx.x * blockDim.x + threadIdx.x;
    long long stride = (long long)gridDim.x * blockDim.x;
    for (; t < n4; t += stride) {
        float4 v = reinterpret_cast<const float4*>(x)[t];
        ushort4 o;
        o.x = f2b(v.x); o.y = f2b(v.y); o.z = f2b(v.z); o.w = f2b(v.w);
        reinterpret_cast<ushort4*>(xb)[t] = o;
    }
}

// Wcat[l][d][k] (k<128 from Wl, else Wr) in bf16.
__global__ __launch_bounds__(256)
void cvt_w_kernel(const float* __restrict__ Wl, const float* __restrict__ Wr,
                  u16* __restrict__ Wcat) {
    int t = blockIdx.x * blockDim.x + threadIdx.x;
    const int NCAT = 3 * 128 * 256;
    if (t < NCAT) {
        int layer = t >> 15;
        int rem = t & 32767;
        int d = rem >> 8;
        int k = rem & 255;
        float v = (k < 128) ? Wl[layer * 16384 + d * 128 + k]
                            : Wr[layer * 16384 + d * 128 + (k - 128)];
        Wcat[t] = f2b(v);
    }
}

// Algebraic post-fusion: Wfuse = W_post2 @ W_post1 (40x128, bf16, padded to
// 48 cols), bfuse = W_post2 @ b_post1 + b_post2 (fp32).
__global__ __launch_bounds__(256)
void wfuse_kernel(const float* __restrict__ W1f, const float* __restrict__ b1,
                  const float* __restrict__ W2, const float* __restrict__ b2,
                  u16* __restrict__ Wfb, float* __restrict__ bfuse) {
    int t = blockIdx.x * 256 + threadIdx.x;
    if (t < 48 * 128) {
        int l = t >> 7, k = t & 127;
        float s = 0.0f;
        if (l < 40) {
            for (int j = 0; j < 128; ++j)
                s += W2[l * 128 + j] * W1f[j * 128 + k];
        }
        Wfb[t] = f2b(s);
    }
    if (blockIdx.x == 0 && threadIdx.x < 40) {
        int l = threadIdx.x;
        float s = b2[l];
        for (int j = 0; j < 128; ++j) s += W2[l * 128 + j] * b1[j];
        bfuse[l] = s;
    }
}

// ---------------------------------------------------------------------------
// Gather aggregation v3: 16B/lane loads — one wave-load covers FOUR edge
// rows (16 lanes x 16B = 256B row). 4x fewer load instructions than v2.
// Group g = lane>>4 handles edges j+g; chunk c = lane&15. 8 fp32 accum/lane;
// cross-group combine via shfl_xor(16/32); lanes 0-15 store uint4.
// ---------------------------------------------------------------------------
#define ACC8(v) do { \
    union { u32 i; float f; } _c; \
    _c.i = (v).x << 16;          acc0 += _c.f; \
    _c.i = (v).x & 0xffff0000u;  acc1 += _c.f; \
    _c.i = (v).y << 16;          acc2 += _c.f; \
    _c.i = (v).y & 0xffff0000u;  acc3 += _c.f; \
    _c.i = (v).z << 16;          acc4 += _c.f; \
    _c.i = (v).z & 0xffff0000u;  acc5 += _c.f; \
    _c.i = (v).w << 16;          acc6 += _c.f; \
    _c.i = (v).w & 0xffff0000u;  acc7 += _c.f; \
} while (0)

__global__ __launch_bounds__(256)
void gather_kernel(const u16* __restrict__ h, const int* __restrict__ rp,
                   const int* __restrict__ ssrc, u16* __restrict__ prop,
                   int n_nodes) {
    int wid = (blockIdx.x * blockDim.x + threadIdx.x) >> 6;
    int lane = threadIdx.x & 63;
    if (wid >= n_nodes) return;
    int beg = rp[wid], end = rp[wid + 1];
    int deg = end - beg;
    int nb = min(deg, 64);
    const int g = lane >> 4;
    const u16* hb = h + (lane & 15) * 8;

    float acc0 = 0, acc1 = 0, acc2 = 0, acc3 = 0;
    float acc4 = 0, acc5 = 0, acc6 = 0, acc7 = 0;

    int sv = (lane < nb) ? ssrc[beg + lane] : 0;   // coalesced edge-index stage

    int j = 0;
    for (; j + 7 < nb; j += 8) {      // 8 edges: 2 x 16B loads in flight
        int s0 = __shfl(sv, j + g);
        int s1 = __shfl(sv, j + 4 + g);
        uint4 v0 = *reinterpret_cast<const uint4*>(hb + (size_t)s0 * DD);
        uint4 v1 = *reinterpret_cast<const uint4*>(hb + (size_t)s1 * DD);
        ACC8(v0);
        ACC8(v1);
    }
    for (; j + 3 < nb; j += 4) {      // 4 edges: 1 load
        int s0 = __shfl(sv, j + g);
        uint4 v0 = *reinterpret_cast<const uint4*>(hb + (size_t)s0 * DD);
        ACC8(v0);
    }
    if (j < nb && g < nb - j) {       // 1-3 leftover edges: groups g<rem
        int s0 = __shfl(sv, j + g);
        uint4 v0 = *reinterpret_cast<const uint4*>(hb + (size_t)s0 * DD);
        ACC8(v0);
    }
    for (int e = beg + 64 + g; e < end; e += 4) {   // deg>64 tail (rare)
        int s0 = ssrc[e];
        uint4 v0 = *reinterpret_cast<const uint4*>(hb + (size_t)s0 * DD);
        ACC8(v0);
    }

    // combine the 4 groups (lanes c, c+16, c+32, c+48)
    acc0 += __shfl_xor(acc0, 16); acc0 += __shfl_xor(acc0, 32);
    acc1 += __shfl_xor(acc1, 16); acc1 += __shfl_xor(acc1, 32);
    acc2 += __shfl_xor(acc2, 16); acc2 += __shfl_xor(acc2, 32);
    acc3 += __shfl_xor(acc3, 16); acc3 += __shfl_xor(acc3, 32);
    acc4 += __shfl_xor(acc4, 16); acc4 += __shfl_xor(acc4, 32);
    acc5 += __shfl_xor(acc5, 16); acc5 += __shfl_xor(acc5, 32);
    acc6 += __shfl_xor(acc6, 16); acc6 += __shfl_xor(acc6, 32);
    acc7 += __shfl_xor(acc7, 16); acc7 += __shfl_xor(acc7, 32);

    if (lane < 16) {
        uint4 o;
        o.x = (u32)f2b(acc0) | ((u32)f2b(acc1) << 16);
        o.y = (u32)f2b(acc2) | ((u32)f2b(acc3) << 16);
        o.z = (u32)f2b(acc4) | ((u32)f2b(acc5) << 16);
        o.w = (u32)f2b(acc6) | ((u32)f2b(acc7) << 16);
        *reinterpret_cast<uint4*>(prop + (size_t)wid * DD + lane * 8) = o;
    }
}

// ---------------------------------------------------------------------------
// MFMA layer GEMM, BM=64: [h|prop] @ Wcat^T + b -> L2-normalize -> ReLU.
// One 64-node strip per block (1563 blocks). 64 MFMA/wave per barrier
// (2x the BM=32 version). 32KB LDS A-tile, same XOR chunk swizzle.
// ---------------------------------------------------------------------------
__global__ __launch_bounds__(256)
void mfma_layer64(const u16* __restrict__ hin, const u16* __restrict__ prop,
                  const u16* __restrict__ Wc, const float* __restrict__ b1,
                  const float* __restrict__ b2, u16* __restrict__ out,
                  int n_nodes) {
    __shared__ char a_s[64 * 512];      // 32 KB
    __shared__ float red_s[64][4];

    const int tid = threadIdx.x;
    const int w = tid >> 6;
    const int l = tid & 63;
    const int q = l >> 4;
    const int c16 = l & 15;

    bf16x8 bfrag[2][8];
    int col[2];
    float bias[2];
    #pragma unroll
    for (int t = 0; t < 2; ++t) {
        col[t] = w * 32 + t * 16 + c16;
        bias[t] = b1[col[t]] + b2[col[t]];
        #pragma unroll
        for (int kk = 0; kk < 8; ++kk)
            bfrag[t][kk] = *reinterpret_cast<const bf16x8*>(
                Wc + (size_t)col[t] * 256 + kk * 32 + q * 8);
    }

    const int base = blockIdx.x * 64;

    // Stage A: 64 rows x 32 chunks of 16B (h chunks 0-15, prop 16-31)
    for (int ci = tid; ci < 2048; ci += 256) {
        int r = ci >> 5, c = ci & 31;
        int node = base + r;
        uint4 v = {0, 0, 0, 0};
        if (node < n_nodes) {
            const u16* src = (c < 16) ? (hin + (size_t)node * DD + c * 8)
                                      : (prop + (size_t)node * DD + (c - 16) * 8);
            v = *reinterpret_cast<const uint4*>(src);
        }
        *reinterpret_cast<uint4*>(a_s + r * 512 + ((c ^ (r & 7)) * 16)) = v;
    }
    __syncthreads();

    f32x4 acc[4][2] = {};
    #pragma unroll
    for (int kk = 0; kk < 8; ++kk) {
        int cc = kk * 4 + q;
        #pragma unroll
        for (int m = 0; m < 4; ++m) {
            int row = m * 16 + c16;
            bf16x8 a = *reinterpret_cast<const bf16x8*>(
                a_s + row * 512 + ((cc ^ (row & 7)) * 16));
            acc[m][0] = __builtin_amdgcn_mfma_f32_16x16x32_bf16(a, bfrag[0][kk], acc[m][0], 0, 0, 0);
            acc[m][1] = __builtin_amdgcn_mfma_f32_16x16x32_bf16(a, bfrag[1][kk], acc[m][1], 0, 0, 0);
        }
    }

    float vals[4][2][4];
    float ss[4][4];
    #pragma unroll
    for (int m = 0; m < 4; ++m) {
        #pragma unroll
        for (int reg = 0; reg < 4; ++reg) {
            float s = 0.0f;
            #pragma unroll
            for (int t = 0; t < 2; ++t) {
                float v = acc[m][t][reg] + bias[t];
                vals[m][t][reg] = v;
                s += v * v;
            }
            s += __shfl_xor(s, 1);
            s += __shfl_xor(s, 2);
            s += __shfl_xor(s, 4);
            s += __shfl_xor(s, 8);
            ss[m][reg] = s;
        }
    }
    if (c16 == 0) {
        #pragma unroll
        for (int m = 0; m < 4; ++m)
            #pragma unroll
            for (int reg = 0; reg < 4; ++reg)
                red_s[m * 16 + q * 4 + reg][w] = ss[m][reg];
    }
    __syncthreads();
    #pragma unroll
    for (int m = 0; m < 4; ++m) {
        #pragma unroll
        for (int reg = 0; reg < 4; ++reg) {
            int row = m * 16 + q * 4 + reg;
            float4 rr = *reinterpret_cast<float4*>(&red_s[row][0]);
            float tot = rr.x + rr.y + rr.z + rr.w;
            float rn = 1.0f / fmaxf(sqrtf(tot), 1e-12f);
            if (base + row < n_nodes) {
                #pragma unroll
                for (int t = 0; t < 2; ++t) {
                    float v = fmaxf(vals[m][t][reg] * rn, 0.0f);
                    out[(size_t)(base + row) * DD + col[t]] = f2b(v);
                }
            }
        }
    }
}

// ---------------------------------------------------------------------------
// Fused post stage: out = log_softmax(h @ Wfuse^T + bfuse), 40 classes.
// ---------------------------------------------------------------------------
__global__ __launch_bounds__(256)
void postfused_kernel(const u16* __restrict__ hin, const u16* __restrict__ Wfb,
                      const float* __restrict__ bfuse, float* __restrict__ out,
                      int n_nodes) {
    __shared__ char a_s[64 * 256];
    const int tid = threadIdx.x;
    const int w = tid >> 6;
    const int l = tid & 63;
    const int q = l >> 4;
    const int c16 = l & 15;

    bf16x8 bfrag[3][4];
    float bias[3];
    int col[3];
    #pragma unroll
    for (int t = 0; t < 3; ++t) {
        col[t] = t * 16 + c16;
        bias[t] = (col[t] < 40) ? bfuse[col[t]] : 0.0f;
        #pragma unroll
        for (int kk = 0; kk < 4; ++kk)
            bfrag[t][kk] = *reinterpret_cast<const bf16x8*>(
                Wfb + col[t] * 128 + kk * 32 + q * 8);
    }

    const int base = blockIdx.x * 64;

    for (int ci = tid; ci < 1024; ci += 256) {
        int r = ci >> 4, c = ci & 15;
        uint4 v = {0, 0, 0, 0};
        if (base + r < n_nodes)
            v = *reinterpret_cast<const uint4*>(hin + (size_t)(base + r) * DD + c * 8);
        *reinterpret_cast<uint4*>(a_s + r * 256 + ((c ^ (r & 7)) * 16)) = v;
    }
    __syncthreads();

    f32x4 acc[3] = {};
    const int arow = w * 16 + c16;
    #pragma unroll
    for (int kk = 0; kk < 4; ++kk) {
        int cc = kk * 4 + q;
        bf16x8 a = *reinterpret_cast<const bf16x8*>(
            a_s + arow * 256 + ((cc ^ (arow & 7)) * 16));
        acc[0] = __builtin_amdgcn_mfma_f32_16x16x32_bf16(a, bfrag[0][kk], acc[0], 0, 0, 0);
        acc[1] = __builtin_amdgcn_mfma_f32_16x16x32_bf16(a, bfrag[1][kk], acc[1], 0, 0, 0);
        acc[2] = __builtin_amdgcn_mfma_f32_16x16x32_bf16(a, bfrag[2][kk], acc[2], 0, 0, 0);
    }

    #pragma unroll
    for (int reg = 0; reg < 4; ++reg) {
        int row = base + w * 16 + q * 4 + reg;
        float v[3];
        float m = -INFINITY;
        #pragma unroll
        for (int t = 0; t < 3; ++t) {
            v[t] = acc[t][reg] + bias[t];
            if (col[t] < 40) m = fmaxf(m, v[t]);
        }
        m = fmaxf(m, __shfl_xor(m, 1));
        m = fmaxf(m, __shfl_xor(m, 2));
        m = fmaxf(m, __shfl_xor(m, 4));
        m = fmaxf(m, __shfl_xor(m, 8));
        float s = 0.0f;
        #pragma unroll
        for (int t = 0; t < 3; ++t)
            if (col[t] < 40) s += expf(v[t] - m);
        s += __shfl_xor(s, 1);
        s += __shfl_xor(s, 2);
        s += __shfl_xor(s, 4);
        s += __shfl_xor(s, 8);
        float lg = logf(s);
        if (row < n_nodes) {
            #pragma unroll
            for (int t = 0; t < 3; ++t)
                if (col[t] < 40)
                    out[(size_t)row * 40 + col[t]] = v[t] - m - lg;
        }
    }
}

// ---------------------------------------------------------------------------
extern "C" void kernel_launch(void* const* d_in, const int* in_sizes, int n_in,
                              void* d_out, int out_size, void* d_ws, size_t ws_size,
                              hipStream_t stream) {
    const float* x   = (const float*)d_in[0];
    const int*   ei  = (const int*)d_in[1];
    const float* Wl  = (const float*)d_in[2];
    const float* bl  = (const float*)d_in[3];
    const float* Wr  = (const float*)d_in[4];
    const float* br  = (const float*)d_in[5];
    const float* W1f = (const float*)d_in[6];
    const float* b1  = (const float*)d_in[7];
    const float* W2  = (const float*)d_in[8];
    const float* b2  = (const float*)d_in[9];
    float* outp = (float*)d_out;

    // Workspace: xb | P | bufA | bufB | Wcat | Wfb+bfuse | bcnt | base |
    //            cursor | row_ptr | ssrc | packed
    u16* xb   = (u16*)d_ws;
    u16* P    = xb + (size_t)NN * DD;
    u16* bufA = P + (size_t)NN * DD;
    u16* bufB = bufA + (size_t)NN * DD;
    u16* Wcat = bufB + (size_t)NN * DD;
    u16* Wfb  = Wcat + 3 * 128 * 256;          // 48*128 used of 128*128 slot
    float* bfuse = (float*)(Wfb + 8192);       // 40 floats, within the slot
    int* bcnt    = (int*)(Wfb + 128 * 128);
    int* base    = bcnt + NBUCK + 1;
    int* cursor  = base + NBUCK + 1;
    int* row_ptr = cursor + NBUCK + 1;
    int* ssrc    = row_ptr + NN + 1;
    u32* packed  = (u32*)(ssrc + NE);

    // CSR build (bucketed counting sort, chunk-reserved scatter)
    hipMemsetAsync(bcnt, 0, (NBUCK + 1) * sizeof(int), stream);
    bcount_kernel<<<128, 256, 0, stream>>>(ei, bcnt, NE);
    bscan_kernel<<<1, 512, 0, stream>>>(bcnt, base, cursor);
    bscatter_kernel<<<(NE + SCHUNK - 1) / SCHUNK, 256, 0, stream>>>(
        ei, cursor, packed, NE);
    blocal_kernel<<<NBUCK, 256, 0, stream>>>(packed, base, row_ptr, ssrc);

    // Conversions + algebraic post-fusion precompute
    cvt_x_kernel<<<12500, 256, 0, stream>>>(x, xb, (long long)NN * DD / 4);
    cvt_w_kernel<<<(3 * 128 * 256 + 255) / 256, 256, 0, stream>>>(Wl, Wr, Wcat);
    wfuse_kernel<<<24, 256, 0, stream>>>(W1f, b1, W2, b2, Wfb, bfuse);

    const int n_strips64 = (NN + 63) / 64;   // 1563
    const int gather_grid = (NN * 64 + 255) / 256;

    const u16* hcur = xb;
    u16* hnext;
    for (int i = 0; i < 3; ++i) {
        hnext = (i == 0) ? bufA : ((hcur == bufA) ? bufB : bufA);
        gather_kernel<<<gather_grid, 256, 0, stream>>>(hcur, row_ptr, ssrc, P, NN);
        mfma_layer64<<<n_strips64, 256, 0, stream>>>(
            hcur, P, Wcat + (size_t)i * 128 * 256,
            bl + (size_t)i * DD, br + (size_t)i * DD, hnext, NN);
        hcur = hnext;
    }
    // Fused post1+post2+log_softmax
    postfused_kernel<<<n_strips64, 256, 0, stream>>>(hcur, Wfb, bfuse, outp, NN);
}

// Round 11
// 344.296 us; speedup vs baseline: 2.0278x; 1.0454x over previous
//
#include <hip/hip_runtime.h>
#include <hip/hip_bf16.h>
#include <cstdint>
#include <cstddef>

#define NN 100000
#define DD 128
#define NE 1600000
#define NPB 196                 // nodes per bucket
#define NBUCK 511               // ceil(NN / NPB)
#define BCAP 6144               // LDS staging capacity per bucket
#define BUCKCAP 4608            // fixed packed/ssrc capacity per bucket (+26 sigma)
#define SCHUNK 8192             // edges per block-chunk in bscatter

typedef short bf16x8 __attribute__((ext_vector_type(8)));
typedef float f32x4 __attribute__((ext_vector_type(4)));
typedef unsigned short u16;
typedef unsigned int u32;

__device__ inline float b2f(u16 u) {
    union { u32 i; float f; } c; c.i = ((u32)u) << 16; return c.f;
}
__device__ inline u16 f2b(float f) {
    __hip_bfloat16 h = __float2bfloat16(f);   // RNE
    return *reinterpret_cast<u16*>(&h);
}

// ---------------------------------------------------------------------------
// CSR build with FIXED-CAPACITY buckets: no bcount/bscan/memset needed.
// cursor[b] starts at b*BUCKCAP (init kernel); bscatter chunk-reserves as in
// round 6; blocal emits per-node beg (row_ptr) AND end (rpe) since padded
// regions break the rp[w+1] convention.
// ---------------------------------------------------------------------------
__global__ __launch_bounds__(256)
void initcur_kernel(int* __restrict__ cur) {
    int t = blockIdx.x * 256 + threadIdx.x;
    if (t < NBUCK) cur[t] = t * BUCKCAP;
}

__global__ __launch_bounds__(256)
void bscatter_kernel(const int* __restrict__ ei, int* __restrict__ cursor,
                     u32* __restrict__ packed, int n_edges) {
    __shared__ int hist[NBUCK];
    const int tid = threadIdx.x;
    const int nchunks = (n_edges + SCHUNK - 1) / SCHUNK;
    for (int ch = blockIdx.x; ch < nchunks; ch += gridDim.x) {
        const int e0 = ch * SCHUNK;
        const int e1 = min(e0 + SCHUNK, n_edges);
        for (int i = tid; i < NBUCK; i += 256) hist[i] = 0;
        __syncthreads();
        for (int e = e0 + tid; e < e1; e += 256)
            atomicAdd(&hist[ei[n_edges + e] / NPB], 1);
        __syncthreads();
        for (int i = tid; i < NBUCK; i += 256) {
            int c = hist[i];
            hist[i] = (c > 0) ? atomicAdd(&cursor[i], c) : 0;
        }
        __syncthreads();
        for (int e = e0 + tid; e < e1; e += 256) {
            int s = ei[e];
            int d = ei[n_edges + e];
            int b = d / NPB;
            int ld = d - b * NPB;
            int pos = atomicAdd(&hist[b], 1);
            packed[pos] = ((u32)ld << 17) | (u32)s;
        }
        __syncthreads();
    }
}

__global__ __launch_bounds__(256)
void blocal_kernel(const u32* __restrict__ packed, const int* __restrict__ cursor,
                   int* __restrict__ row_ptr, int* __restrict__ rpe,
                   int* __restrict__ ssrc) {
    __shared__ int out_s[BCAP];
    __shared__ int cur_s[NPB];
    __shared__ int excl_s[NPB];
    __shared__ int ws[4];
    __shared__ int wexc[4];

    const int b = blockIdx.x;
    const int tid = threadIdx.x;
    const int lane = tid & 63, wv = tid >> 6;
    const int pbase = b * BUCKCAP;
    const int cnt = cursor[b] - pbase;

    if (tid < NPB) cur_s[tid] = 0;
    __syncthreads();
    for (int i = tid; i < cnt; i += 256)
        atomicAdd(&cur_s[packed[pbase + i] >> 17], 1);
    __syncthreads();

    int v = (tid < NPB) ? cur_s[tid] : 0;
    int inc = v;
    #pragma unroll
    for (int o = 1; o < 64; o <<= 1) {
        int u = __shfl_up(inc, o);
        if (lane >= o) inc += u;
    }
    if (lane == 63) ws[wv] = inc;
    __syncthreads();
    if (tid == 0) {
        int s = 0;
        #pragma unroll
        for (int k = 0; k < 4; ++k) { wexc[k] = s; s += ws[k]; }
    }
    __syncthreads();
    int excl = inc - v + wexc[wv];
    if (tid < NPB) excl_s[tid] = excl;
    int gnode = b * NPB + tid;
    if (tid < NPB && gnode < NN) {
        row_ptr[gnode] = pbase + excl;
        rpe[gnode] = pbase + excl + v;
    }
    __syncthreads();
    if (tid < NPB) cur_s[tid] = excl_s[tid];
    __syncthreads();

    if (cnt <= BCAP) {
        for (int i = tid; i < cnt; i += 256) {
            u32 p = packed[pbase + i];
            int pos = atomicAdd(&cur_s[p >> 17], 1);
            out_s[pos] = (int)(p & 0x1FFFF);
        }
        __syncthreads();
        for (int i = tid; i < cnt; i += 256) ssrc[pbase + i] = out_s[i];
    } else {
        for (int i = tid; i < cnt; i += 256) {
            u32 p = packed[pbase + i];
            int pos = atomicAdd(&cur_s[p >> 17], 1);
            ssrc[pbase + pos] = (int)(p & 0x1FFFF);
        }
    }
}

// ---------------------------------------------------------------------------
// Conversions
// ---------------------------------------------------------------------------
__global__ __launch_bounds__(256)
void cvt_x_kernel(const float* __restrict__ x, u16* __restrict__ xb, long long n4) {
    long long t = (long long)blockIdx.x * blockDim.x + threadIdx.x;
    long long stride = (long long)gridDim.x * blockDim.x;
    for (; t < n4; t += stride) {
        float4 v = reinterpret_cast<const float4*>(x)[t];
        ushort4 o;
        o.x = f2b(v.x); o.y = f2b(v.y); o.z = f2b(v.z); o.w = f2b(v.w);
        reinterpret_cast<ushort4*>(xb)[t] = o;
    }
}

__global__ __launch_bounds__(256)
void cvt_w_kernel(const float* __restrict__ Wl, const float* __restrict__ Wr,
                  u16* __restrict__ Wcat) {
    int t = blockIdx.x * blockDim.x + threadIdx.x;
    const int NCAT = 3 * 128 * 256;
    if (t < NCAT) {
        int layer = t >> 15;
        int rem = t & 32767;
        int d = rem >> 8;
        int k = rem & 255;
        float v = (k < 128) ? Wl[layer * 16384 + d * 128 + k]
                            : Wr[layer * 16384 + d * 128 + (k - 128)];
        Wcat[t] = f2b(v);
    }
}

__global__ __launch_bounds__(256)
void wfuse_kernel(const float* __restrict__ W1f, const float* __restrict__ b1,
                  const float* __restrict__ W2, const float* __restrict__ b2,
                  u16* __restrict__ Wfb, float* __restrict__ bfuse) {
    int t = blockIdx.x * 256 + threadIdx.x;
    if (t < 48 * 128) {
        int l = t >> 7, k = t & 127;
        float s = 0.0f;
        if (l < 40) {
            for (int j = 0; j < 128; ++j)
                s += W2[l * 128 + j] * W1f[j * 128 + k];
        }
        Wfb[t] = f2b(s);
    }
    if (blockIdx.x == 0 && threadIdx.x < 40) {
        int l = threadIdx.x;
        float s = b2[l];
        for (int j = 0; j < 128; ++j) s += W2[l * 128 + j] * b1[j];
        bfuse[l] = s;
    }
}

// ---------------------------------------------------------------------------
// Gather v4: 16B/lane loads, FOUR loads in flight (16 edges/iter — one
// iteration covers a mean-degree node). Explicit (beg,end) per node.
// ---------------------------------------------------------------------------
#define ACC8(v) do { \
    union { u32 i; float f; } _c; \
    _c.i = (v).x << 16;          acc0 += _c.f; \
    _c.i = (v).x & 0xffff0000u;  acc1 += _c.f; \
    _c.i = (v).y << 16;          acc2 += _c.f; \
    _c.i = (v).y & 0xffff0000u;  acc3 += _c.f; \
    _c.i = (v).z << 16;          acc4 += _c.f; \
    _c.i = (v).z & 0xffff0000u;  acc5 += _c.f; \
    _c.i = (v).w << 16;          acc6 += _c.f; \
    _c.i = (v).w & 0xffff0000u;  acc7 += _c.f; \
} while (0)

__global__ __launch_bounds__(256)
void gather_kernel(const u16* __restrict__ h, const int* __restrict__ rp,
                   const int* __restrict__ rpe, const int* __restrict__ ssrc,
                   u16* __restrict__ prop, int n_nodes) {
    int wid = (blockIdx.x * blockDim.x + threadIdx.x) >> 6;
    int lane = threadIdx.x & 63;
    if (wid >= n_nodes) return;
    int beg = rp[wid], end = rpe[wid];
    int deg = end - beg;
    int nb = min(deg, 64);
    const int g = lane >> 4;
    const u16* hb = h + (lane & 15) * 8;

    float acc0 = 0, acc1 = 0, acc2 = 0, acc3 = 0;
    float acc4 = 0, acc5 = 0, acc6 = 0, acc7 = 0;

    int sv = (lane < nb) ? ssrc[beg + lane] : 0;

    int j = 0;
    for (; j + 15 < nb; j += 16) {    // 16 edges: 4 x 16B loads in flight
        int s0 = __shfl(sv, j + g);
        int s1 = __shfl(sv, j + 4 + g);
        int s2 = __shfl(sv, j + 8 + g);
        int s3 = __shfl(sv, j + 12 + g);
        uint4 v0 = *reinterpret_cast<const uint4*>(hb + (size_t)s0 * DD);
        uint4 v1 = *reinterpret_cast<const uint4*>(hb + (size_t)s1 * DD);
        uint4 v2 = *reinterpret_cast<const uint4*>(hb + (size_t)s2 * DD);
        uint4 v3 = *reinterpret_cast<const uint4*>(hb + (size_t)s3 * DD);
        ACC8(v0);
        ACC8(v1);
        ACC8(v2);
        ACC8(v3);
    }
    for (; j + 7 < nb; j += 8) {
        int s0 = __shfl(sv, j + g);
        int s1 = __shfl(sv, j + 4 + g);
        uint4 v0 = *reinterpret_cast<const uint4*>(hb + (size_t)s0 * DD);
        uint4 v1 = *reinterpret_cast<const uint4*>(hb + (size_t)s1 * DD);
        ACC8(v0);
        ACC8(v1);
    }
    for (; j + 3 < nb; j += 4) {
        int s0 = __shfl(sv, j + g);
        uint4 v0 = *reinterpret_cast<const uint4*>(hb + (size_t)s0 * DD);
        ACC8(v0);
    }
    if (j < nb && g < nb - j) {
        int s0 = __shfl(sv, j + g);
        uint4 v0 = *reinterpret_cast<const uint4*>(hb + (size_t)s0 * DD);
        ACC8(v0);
    }
    for (int e = beg + 64 + g; e < end; e += 4) {   // deg>64 tail (rare)
        int s0 = ssrc[e];
        uint4 v0 = *reinterpret_cast<const uint4*>(hb + (size_t)s0 * DD);
        ACC8(v0);
    }

    acc0 += __shfl_xor(acc0, 16); acc0 += __shfl_xor(acc0, 32);
    acc1 += __shfl_xor(acc1, 16); acc1 += __shfl_xor(acc1, 32);
    acc2 += __shfl_xor(acc2, 16); acc2 += __shfl_xor(acc2, 32);
    acc3 += __shfl_xor(acc3, 16); acc3 += __shfl_xor(acc3, 32);
    acc4 += __shfl_xor(acc4, 16); acc4 += __shfl_xor(acc4, 32);
    acc5 += __shfl_xor(acc5, 16); acc5 += __shfl_xor(acc5, 32);
    acc6 += __shfl_xor(acc6, 16); acc6 += __shfl_xor(acc6, 32);
    acc7 += __shfl_xor(acc7, 16); acc7 += __shfl_xor(acc7, 32);

    if (lane < 16) {
        uint4 o;
        o.x = (u32)f2b(acc0) | ((u32)f2b(acc1) << 16);
        o.y = (u32)f2b(acc2) | ((u32)f2b(acc3) << 16);
        o.z = (u32)f2b(acc4) | ((u32)f2b(acc5) << 16);
        o.w = (u32)f2b(acc6) | ((u32)f2b(acc7) << 16);
        *reinterpret_cast<uint4*>(prop + (size_t)wid * DD + lane * 8) = o;
    }
}

// ---------------------------------------------------------------------------
// MFMA layer GEMM, BM=64 (round-10 proven).
// ---------------------------------------------------------------------------
__global__ __launch_bounds__(256)
void mfma_layer64(const u16* __restrict__ hin, const u16* __restrict__ prop,
                  const u16* __restrict__ Wc, const float* __restrict__ b1,
                  const float* __restrict__ b2, u16* __restrict__ out,
                  int n_nodes) {
    __shared__ char a_s[64 * 512];      // 32 KB
    __shared__ float red_s[64][4];

    const int tid = threadIdx.x;
    const int w = tid >> 6;
    const int l = tid & 63;
    const int q = l >> 4;
    const int c16 = l & 15;

    bf16x8 bfrag[2][8];
    int col[2];
    float bias[2];
    #pragma unroll
    for (int t = 0; t < 2; ++t) {
        col[t] = w * 32 + t * 16 + c16;
        bias[t] = b1[col[t]] + b2[col[t]];
        #pragma unroll
        for (int kk = 0; kk < 8; ++kk)
            bfrag[t][kk] = *reinterpret_cast<const bf16x8*>(
                Wc + (size_t)col[t] * 256 + kk * 32 + q * 8);
    }

    const int base = blockIdx.x * 64;

    for (int ci = tid; ci < 2048; ci += 256) {
        int r = ci >> 5, c = ci & 31;
        int node = base + r;
        uint4 v = {0, 0, 0, 0};
        if (node < n_nodes) {
            const u16* src = (c < 16) ? (hin + (size_t)node * DD + c * 8)
                                      : (prop + (size_t)node * DD + (c - 16) * 8);
            v = *reinterpret_cast<const uint4*>(src);
        }
        *reinterpret_cast<uint4*>(a_s + r * 512 + ((c ^ (r & 7)) * 16)) = v;
    }
    __syncthreads();

    f32x4 acc[4][2] = {};
    #pragma unroll
    for (int kk = 0; kk < 8; ++kk) {
        int cc = kk * 4 + q;
        #pragma unroll
        for (int m = 0; m < 4; ++m) {
            int row = m * 16 + c16;
            bf16x8 a = *reinterpret_cast<const bf16x8*>(
                a_s + row * 512 + ((cc ^ (row & 7)) * 16));
            acc[m][0] = __builtin_amdgcn_mfma_f32_16x16x32_bf16(a, bfrag[0][kk], acc[m][0], 0, 0, 0);
            acc[m][1] = __builtin_amdgcn_mfma_f32_16x16x32_bf16(a, bfrag[1][kk], acc[m][1], 0, 0, 0);
        }
    }

    float vals[4][2][4];
    float ss[4][4];
    #pragma unroll
    for (int m = 0; m < 4; ++m) {
        #pragma unroll
        for (int reg = 0; reg < 4; ++reg) {
            float s = 0.0f;
            #pragma unroll
            for (int t = 0; t < 2; ++t) {
                float v = acc[m][t][reg] + bias[t];
                vals[m][t][reg] = v;
                s += v * v;
            }
            s += __shfl_xor(s, 1);
            s += __shfl_xor(s, 2);
            s += __shfl_xor(s, 4);
            s += __shfl_xor(s, 8);
            ss[m][reg] = s;
        }
    }
    if (c16 == 0) {
        #pragma unroll
        for (int m = 0; m < 4; ++m)
            #pragma unroll
            for (int reg = 0; reg < 4; ++reg)
                red_s[m * 16 + q * 4 + reg][w] = ss[m][reg];
    }
    __syncthreads();
    #pragma unroll
    for (int m = 0; m < 4; ++m) {
        #pragma unroll
        for (int reg = 0; reg < 4; ++reg) {
            int row = m * 16 + q * 4 + reg;
            float4 rr = *reinterpret_cast<float4*>(&red_s[row][0]);
            float tot = rr.x + rr.y + rr.z + rr.w;
            float rn = 1.0f / fmaxf(sqrtf(tot), 1e-12f);
            if (base + row < n_nodes) {
                #pragma unroll
                for (int t = 0; t < 2; ++t) {
                    float v = fmaxf(vals[m][t][reg] * rn, 0.0f);
                    out[(size_t)(base + row) * DD + col[t]] = f2b(v);
                }
            }
        }
    }
}

// ---------------------------------------------------------------------------
// Fused post stage: out = log_softmax(h @ Wfuse^T + bfuse), 40 classes.
// ---------------------------------------------------------------------------
__global__ __launch_bounds__(256)
void postfused_kernel(const u16* __restrict__ hin, const u16* __restrict__ Wfb,
                      const float* __restrict__ bfuse, float* __restrict__ out,
                      int n_nodes) {
    __shared__ char a_s[64 * 256];
    const int tid = threadIdx.x;
    const int w = tid >> 6;
    const int l = tid & 63;
    const int q = l >> 4;
    const int c16 = l & 15;

    bf16x8 bfrag[3][4];
    float bias[3];
    int col[3];
    #pragma unroll
    for (int t = 0; t < 3; ++t) {
        col[t] = t * 16 + c16;
        bias[t] = (col[t] < 40) ? bfuse[col[t]] : 0.0f;
        #pragma unroll
        for (int kk = 0; kk < 4; ++kk)
            bfrag[t][kk] = *reinterpret_cast<const bf16x8*>(
                Wfb + col[t] * 128 + kk * 32 + q * 8);
    }

    const int base = blockIdx.x * 64;

    for (int ci = tid; ci < 1024; ci += 256) {
        int r = ci >> 4, c = ci & 15;
        uint4 v = {0, 0, 0, 0};
        if (base + r < n_nodes)
            v = *reinterpret_cast<const uint4*>(hin + (size_t)(base + r) * DD + c * 8);
        *reinterpret_cast<uint4*>(a_s + r * 256 + ((c ^ (r & 7)) * 16)) = v;
    }
    __syncthreads();

    f32x4 acc[3] = {};
    const int arow = w * 16 + c16;
    #pragma unroll
    for (int kk = 0; kk < 4; ++kk) {
        int cc = kk * 4 + q;
        bf16x8 a = *reinterpret_cast<const bf16x8*>(
            a_s + arow * 256 + ((cc ^ (arow & 7)) * 16));
        acc[0] = __builtin_amdgcn_mfma_f32_16x16x32_bf16(a, bfrag[0][kk], acc[0], 0, 0, 0);
        acc[1] = __builtin_amdgcn_mfma_f32_16x16x32_bf16(a, bfrag[1][kk], acc[1], 0, 0, 0);
        acc[2] = __builtin_amdgcn_mfma_f32_16x16x32_bf16(a, bfrag[2][kk], acc[2], 0, 0, 0);
    }

    #pragma unroll
    for (int reg = 0; reg < 4; ++reg) {
        int row = base + w * 16 + q * 4 + reg;
        float v[3];
        float m = -INFINITY;
        #pragma unroll
        for (int t = 0; t < 3; ++t) {
            v[t] = acc[t][reg] + bias[t];
            if (col[t] < 40) m = fmaxf(m, v[t]);
        }
        m = fmaxf(m, __shfl_xor(m, 1));
        m = fmaxf(m, __shfl_xor(m, 2));
        m = fmaxf(m, __shfl_xor(m, 4));
        m = fmaxf(m, __shfl_xor(m, 8));
        float s = 0.0f;
        #pragma unroll
        for (int t = 0; t < 3; ++t)
            if (col[t] < 40) s += expf(v[t] - m);
        s += __shfl_xor(s, 1);
        s += __shfl_xor(s, 2);
        s += __shfl_xor(s, 4);
        s += __shfl_xor(s, 8);
        float lg = logf(s);
        if (row < n_nodes) {
            #pragma unroll
            for (int t = 0; t < 3; ++t)
                if (col[t] < 40)
                    out[(size_t)row * 40 + col[t]] = v[t] - m - lg;
        }
    }
}

// ---------------------------------------------------------------------------
extern "C" void kernel_launch(void* const* d_in, const int* in_sizes, int n_in,
                              void* d_out, int out_size, void* d_ws, size_t ws_size,
                              hipStream_t stream) {
    const float* x   = (const float*)d_in[0];
    const int*   ei  = (const int*)d_in[1];
    const float* Wl  = (const float*)d_in[2];
    const float* bl  = (const float*)d_in[3];
    const float* Wr  = (const float*)d_in[4];
    const float* br  = (const float*)d_in[5];
    const float* W1f = (const float*)d_in[6];
    const float* b1  = (const float*)d_in[7];
    const float* W2  = (const float*)d_in[8];
    const float* b2  = (const float*)d_in[9];
    float* outp = (float*)d_out;

    // Workspace: xb | P | bufA | bufB | Wcat | Wfb+bfuse | cursor | row_ptr |
    //            rpe | ssrc(padded) | packed(padded)
    u16* xb   = (u16*)d_ws;
    u16* P    = xb + (size_t)NN * DD;
    u16* bufA = P + (size_t)NN * DD;
    u16* bufB = bufA + (size_t)NN * DD;
    u16* Wcat = bufB + (size_t)NN * DD;
    u16* Wfb  = Wcat + 3 * 128 * 256;          // 48*128 used of 128*128 slot
    float* bfuse = (float*)(Wfb + 8192);
    int* cursor  = (int*)(Wfb + 128 * 128);
    int* row_ptr = cursor + NBUCK + 1;
    int* rpe     = row_ptr + NN;
    int* ssrc    = rpe + NN;
    u32* packed  = (u32*)(ssrc + NBUCK * BUCKCAP);

    // CSR build: fixed-capacity buckets (no count/scan passes)
    initcur_kernel<<<2, 256, 0, stream>>>(cursor);
    bscatter_kernel<<<(NE + SCHUNK - 1) / SCHUNK, 256, 0, stream>>>(
        ei, cursor, packed, NE);
    blocal_kernel<<<NBUCK, 256, 0, stream>>>(packed, cursor, row_ptr, rpe, ssrc);

    // Conversions + algebraic post-fusion precompute
    cvt_x_kernel<<<12500, 256, 0, stream>>>(x, xb, (long long)NN * DD / 4);
    cvt_w_kernel<<<(3 * 128 * 256 + 255) / 256, 256, 0, stream>>>(Wl, Wr, Wcat);
    wfuse_kernel<<<24, 256, 0, stream>>>(W1f, b1, W2, b2, Wfb, bfuse);

    const int n_strips64 = (NN + 63) / 64;   // 1563
    const int gather_grid = (NN * 64 + 255) / 256;

    const u16* hcur = xb;
    u16* hnext;
    for (int i = 0; i < 3; ++i) {
        hnext = (i == 0) ? bufA : ((hcur == bufA) ? bufB : bufA);
        gather_kernel<<<gather_grid, 256, 0, stream>>>(
            hcur, row_ptr, rpe, ssrc, P, NN);
        mfma_layer64<<<n_strips64, 256, 0, stream>>>(
            hcur, P, Wcat + (size_t)i * 128 * 256,
            bl + (size_t)i * DD, br + (size_t)i * DD, hnext, NN);
        hcur = hnext;
    }
    // Fused post1+post2+log_softmax
    postfused_kernel<<<n_strips64, 256, 0, stream>>>(hcur, Wfb, bfuse, outp, NN);
}